// Round 2
// baseline (418.707 us; speedup 1.0000x reference)
//
#include <hip/hip_runtime.h>
#include <hip/hip_bf16.h>
#include <cstdint>
#include <math.h>

typedef __hip_bfloat16 bf16_t;
typedef __attribute__((ext_vector_type(8))) __bf16 bf16x8;
typedef __attribute__((ext_vector_type(4))) float f32x4;

static_assert(sizeof(bf16x8) == 16, "bf16x8 must be 4 VGPRs");

static constexpr int DD = 1024;   // D
static constexpr int HH = 4096;   // H = 4*D

// async global->LDS, 16B per lane.
// Global ptr: via uintptr_t (strips const; inttoptr exact for AS1).
// LDS ptr: explicit 32-bit truncation == LLVM's generic->p3 addrspacecast lowering.
#define GLD16(gp, lp)                                                                              \
  __builtin_amdgcn_global_load_lds(                                                                \
      (__attribute__((address_space(1))) void*)(uintptr_t)(gp),                                    \
      (__attribute__((address_space(3))) void*)(uint32_t)(uintptr_t)(lp), 16, 0, 0)

// ---------------- fp32 -> bf16 hi/lo split (for x) ----------------
__global__ __launch_bounds__(256) void k_split_x(const float* __restrict__ x,
                                                 bf16_t* __restrict__ xh,
                                                 bf16_t* __restrict__ xl, int n4) {
  int i = blockIdx.x * 256 + threadIdx.x;
  const int stride = gridDim.x * 256;
  for (; i < n4; i += stride) {
    const float4 v = reinterpret_cast<const float4*>(x)[i];
    float vv[4] = {v.x, v.y, v.z, v.w};
    union { bf16_t b[4]; short4 s; } H, L;
#pragma unroll
    for (int j = 0; j < 4; ++j) {
      H.b[j] = __float2bfloat16(vv[j]);
      L.b[j] = __float2bfloat16(vv[j] - __bfloat162float(H.b[j]));
    }
    reinterpret_cast<short4*>(xh)[i] = H.s;
    reinterpret_cast<short4*>(xl)[i] = L.s;
  }
}

// ---------------- transpose + convert weights: W[K][N] f32 -> WT[N][K] bf16 (optional lo) -----
template <bool SPLIT>
__global__ __launch_bounds__(256) void k_transpose(const float* __restrict__ W,
                                                   bf16_t* __restrict__ Th,
                                                   bf16_t* __restrict__ Tl, int K, int N) {
  __shared__ float tile[32][33];
  const int n0 = blockIdx.x * 32, k0 = blockIdx.y * 32;
  const int tx = threadIdx.x, ty = threadIdx.y;  // block (32,8)
#pragma unroll
  for (int r = 0; r < 4; ++r) {
    const int k = ty + r * 8;
    tile[k][tx] = W[(size_t)(k0 + k) * N + n0 + tx];
  }
  __syncthreads();
#pragma unroll
  for (int r = 0; r < 4; ++r) {
    const int n = ty + r * 8;
    const float v = tile[tx][n];
    const bf16_t h = __float2bfloat16(v);
    Th[(size_t)(n0 + n) * K + k0 + tx] = h;
    if (SPLIT) Tl[(size_t)(n0 + n) * K + k0 + tx] = __float2bfloat16(v - __bfloat162float(h));
  }
}

// ---------------- GEMM: C[M,N] = A[M,K] * B[K,N], B given pre-transposed BT[N][K] --------------
// EPI 1: write Cf=v (f32) and Cb=bf16(v)            (z for residual + z for GEMM2)
// EPI 2: write Cb=bf16(gelu_exact(v+bias[c]))       (h)
// EPI 3: write Cf=v+bias[c]                         (y)
// SPLIT: 3-pass hi/lo accumulation (A=Ah+Al, B=Bh+Bl; drop lo*lo term)
template <int EPI, bool SPLIT>
__global__ __launch_bounds__(256) void k_gemm(const bf16_t* __restrict__ Ah,
                                              const bf16_t* __restrict__ Al,
                                              const bf16_t* __restrict__ BTh,
                                              const bf16_t* __restrict__ BTl,
                                              const float* __restrict__ bias,
                                              float* __restrict__ Cf,
                                              bf16_t* __restrict__ Cb, int M, int N, int K) {
  constexpr int BM = 128, BN = 128, BK = 32;
  __shared__ __align__(16) bf16_t sAh[BM * BK];
  __shared__ __align__(16) bf16_t sBh[BN * BK];
  __shared__ __align__(16) bf16_t sAl[SPLIT ? BM * BK : 8];
  __shared__ __align__(16) bf16_t sBl[SPLIT ? BN * BK : 8];

  const int nbn = N / BN;
  const int nwg = gridDim.x;  // divisible by 8 for all our launches
  const int wg = blockIdx.x;
  const int cpx = nwg >> 3;
  const int swz = (wg & 7) * cpx + (wg >> 3);  // bijective XCD swizzle (nwg % 8 == 0)
  const int bm = swz / nbn, bn = swz % nbn;

  const int t = threadIdx.x;
  const int l = t & 63;
  const int w = t >> 6;
  const int wr = (w >> 1) * 64, wc = (w & 1) * 64;

  const size_t Abase = (size_t)bm * BM * K;
  const size_t Bbase = (size_t)bn * BN * K;

  // staging map: thread t covers row t>>2, k-elements (t&3)*8 (16B); second pass row+64.
  // LDS offset = t*16 bytes -> per-wave uniform base + lane*16 (linear, GLD-compatible).
  const int r0 = t >> 2, kc0 = (t & 3) * 8;
  const int r1 = r0 + 64;

  f32x4 acc[4][4] = {};
  const int lm = l & 15;
  const int kb8 = (l >> 4) * 8;

  const int nk = K / BK;
  for (int kt = 0; kt < nk; ++kt) {
    const size_t gk = (size_t)kt * BK;
    GLD16(Ah + Abase + (size_t)r0 * K + gk + kc0, &sAh[r0 * BK + kc0]);
    GLD16(Ah + Abase + (size_t)r1 * K + gk + kc0, &sAh[r1 * BK + kc0]);
    GLD16(BTh + Bbase + (size_t)r0 * K + gk + kc0, &sBh[r0 * BK + kc0]);
    GLD16(BTh + Bbase + (size_t)r1 * K + gk + kc0, &sBh[r1 * BK + kc0]);
    if (SPLIT) {
      GLD16(Al + Abase + (size_t)r0 * K + gk + kc0, &sAl[r0 * BK + kc0]);
      GLD16(Al + Abase + (size_t)r1 * K + gk + kc0, &sAl[r1 * BK + kc0]);
      GLD16(BTl + Bbase + (size_t)r0 * K + gk + kc0, &sBl[r0 * BK + kc0]);
      GLD16(BTl + Bbase + (size_t)r1 * K + gk + kc0, &sBl[r1 * BK + kc0]);
    }
    __syncthreads();  // compiler drains vmcnt before s_barrier

    bf16x8 a[4], b[4];
#pragma unroll
    for (int m = 0; m < 4; ++m)
      a[m] = *reinterpret_cast<const bf16x8*>(&sAh[(wr + m * 16 + lm) * BK + kb8]);
#pragma unroll
    for (int n = 0; n < 4; ++n)
      b[n] = *reinterpret_cast<const bf16x8*>(&sBh[(wc + n * 16 + lm) * BK + kb8]);
#pragma unroll
    for (int m = 0; m < 4; ++m)
#pragma unroll
      for (int n = 0; n < 4; ++n)
        acc[m][n] = __builtin_amdgcn_mfma_f32_16x16x32_bf16(a[m], b[n], acc[m][n], 0, 0, 0);

    if (SPLIT) {
      bf16x8 al_[4], bl_[4];
#pragma unroll
      for (int m = 0; m < 4; ++m)
        al_[m] = *reinterpret_cast<const bf16x8*>(&sAl[(wr + m * 16 + lm) * BK + kb8]);
#pragma unroll
      for (int n = 0; n < 4; ++n)
        bl_[n] = *reinterpret_cast<const bf16x8*>(&sBl[(wc + n * 16 + lm) * BK + kb8]);
#pragma unroll
      for (int m = 0; m < 4; ++m)
#pragma unroll
        for (int n = 0; n < 4; ++n) {
          acc[m][n] = __builtin_amdgcn_mfma_f32_16x16x32_bf16(a[m], bl_[n], acc[m][n], 0, 0, 0);
          acc[m][n] = __builtin_amdgcn_mfma_f32_16x16x32_bf16(al_[m], b[n], acc[m][n], 0, 0, 0);
        }
    }
    __syncthreads();
  }

  // C/D layout (m89-verified): col = lane&15, row = (lane>>4)*4 + j
  const int cr = (l >> 4) * 4;
#pragma unroll
  for (int m = 0; m < 4; ++m) {
#pragma unroll
    for (int n = 0; n < 4; ++n) {
      const int c = bn * BN + wc + n * 16 + lm;
#pragma unroll
      for (int j = 0; j < 4; ++j) {
        const int r = bm * BM + wr + m * 16 + cr + j;
        const size_t idx = (size_t)r * N + c;
        const float v = acc[m][n][j];
        if (EPI == 1) {
          Cf[idx] = v;
          Cb[idx] = __float2bfloat16(v);
        } else if (EPI == 2) {
          const float u = v + bias[c];
          const float g = 0.5f * u * (1.0f + erff(u * 0.70710678118654752f));
          Cb[idx] = __float2bfloat16(g);
        } else {
          Cf[idx] = v + bias[c];
        }
      }
    }
  }
}

// ---------------- LayerNorm(y) fused with residual: out = z + tanh(alpha)*ln ----------------
__global__ __launch_bounds__(256) void k_ln_res(const float* __restrict__ y,
                                                const float* __restrict__ z,
                                                const float* __restrict__ gamma,
                                                const float* __restrict__ beta,
                                                const float* __restrict__ alpha,
                                                float* __restrict__ out) {
  const int row = blockIdx.x;
  const int t = threadIdx.x;  // 256 threads * 4 floats = 1024 = D
  const float4 v = reinterpret_cast<const float4*>(y + (size_t)row * DD)[t];
  float s = v.x + v.y + v.z + v.w;
  float q = v.x * v.x + v.y * v.y + v.z * v.z + v.w * v.w;
#pragma unroll
  for (int m = 1; m < 64; m <<= 1) {
    s += __shfl_xor(s, m, 64);
    q += __shfl_xor(q, m, 64);
  }
  __shared__ float ss[4], sq[4];
  if ((t & 63) == 0) { ss[t >> 6] = s; sq[t >> 6] = q; }
  __syncthreads();
  s = ss[0] + ss[1] + ss[2] + ss[3];
  q = sq[0] + sq[1] + sq[2] + sq[3];
  const float mu = s * (1.0f / DD);
  const float var = fmaxf(q * (1.0f / DD) - mu * mu, 0.0f);
  const float rs = rsqrtf(var + 1e-5f);
  const float4 g = reinterpret_cast<const float4*>(gamma)[t];
  const float4 bb = reinterpret_cast<const float4*>(beta)[t];
  const float4 aa = reinterpret_cast<const float4*>(alpha)[t];
  const float4 zz = reinterpret_cast<const float4*>(z + (size_t)row * DD)[t];
  float4 o;
  o.x = zz.x + tanhf(aa.x) * ((v.x - mu) * rs * g.x + bb.x);
  o.y = zz.y + tanhf(aa.y) * ((v.y - mu) * rs * g.y + bb.y);
  o.z = zz.z + tanhf(aa.z) * ((v.z - mu) * rs * g.z + bb.z);
  o.w = zz.w + tanhf(aa.w) * ((v.w - mu) * rs * g.w + bb.w);
  reinterpret_cast<float4*>(out + (size_t)row * DD)[t] = o;
}

extern "C" void kernel_launch(void* const* d_in, const int* in_sizes, int n_in, void* d_out,
                              int out_size, void* d_ws, size_t ws_size, hipStream_t stream) {
  const float* x   = (const float*)d_in[0];
  const float* thQ = (const float*)d_in[1];
  const float* W1  = (const float*)d_in[2];
  const float* b1  = (const float*)d_in[3];
  const float* W2  = (const float*)d_in[4];
  const float* b2  = (const float*)d_in[5];
  const float* gam = (const float*)d_in[6];
  const float* bet = (const float*)d_in[7];
  const float* alp = (const float*)d_in[8];
  float* out = (float*)d_out;

  const int M = in_sizes[0] / DD;  // B*V*T = 8192

  char* ws = (char*)d_ws;
  size_t off = 0;
  auto take = [&](size_t bytes) -> char* {
    char* p = ws + off;
    off += (bytes + 255) & ~(size_t)255;
    return p;
  };
  bf16_t* xh  = (bf16_t*)take((size_t)M * DD * 2);
  bf16_t* xl  = (bf16_t*)take((size_t)M * DD * 2);
  bf16_t* qTh = (bf16_t*)take((size_t)DD * DD * 2);
  bf16_t* qTl = (bf16_t*)take((size_t)DD * DD * 2);
  bf16_t* w1T = (bf16_t*)take((size_t)DD * HH * 2);
  bf16_t* w2T = (bf16_t*)take((size_t)HH * DD * 2);
  float*  zf  = (float*)take((size_t)M * DD * 4);
  bf16_t* zb  = (bf16_t*)take((size_t)M * DD * 2);
  bf16_t* hb  = (bf16_t*)take((size_t)M * HH * 2);
  float*  yf  = (float*)take((size_t)M * DD * 4);
  // total ~196 MB of d_ws

  // prep: conversions / transposes
  hipLaunchKernelGGL(k_split_x, dim3(2048), dim3(256), 0, stream, x, xh, xl, M * DD / 4);
  hipLaunchKernelGGL((k_transpose<true>), dim3(DD / 32, DD / 32), dim3(32, 8), 0, stream,
                     thQ, qTh, qTl, DD, DD);
  hipLaunchKernelGGL((k_transpose<false>), dim3(HH / 32, DD / 32), dim3(32, 8), 0, stream,
                     W1, w1T, (bf16_t*)nullptr, DD, HH);
  hipLaunchKernelGGL((k_transpose<false>), dim3(DD / 32, HH / 32), dim3(32, 8), 0, stream,
                     W2, w2T, (bf16_t*)nullptr, HH, DD);

  // z = x @ thetaQ  (split 3-pass for fp32-grade accuracy; z feeds output directly)
  hipLaunchKernelGGL((k_gemm<1, true>), dim3((M / 128) * (DD / 128)), dim3(256), 0, stream,
                     xh, xl, qTh, qTl, (const float*)nullptr, zf, zb, M, DD, DD);
  // h = gelu(z @ W1 + b1)   (bf16; error damped x100 by tanh(alpha) after LN)
  hipLaunchKernelGGL((k_gemm<2, false>), dim3((M / 128) * (HH / 128)), dim3(256), 0, stream,
                     zb, (const bf16_t*)nullptr, w1T, (const bf16_t*)nullptr, b1,
                     (float*)nullptr, hb, M, HH, DD);
  // y = h @ W2 + b2
  hipLaunchKernelGGL((k_gemm<3, false>), dim3((M / 128) * (DD / 128)), dim3(256), 0, stream,
                     hb, (const bf16_t*)nullptr, w2T, (const bf16_t*)nullptr, b2,
                     yf, (bf16_t*)nullptr, M, DD, HH);
  // out = z + tanh(alpha) * LayerNorm(y)
  hipLaunchKernelGGL(k_ln_res, dim3(M), dim3(256), 0, stream, yf, zf, gam, bet, alp, out);
}

// Round 3
// 399.253 us; speedup vs baseline: 1.0487x; 1.0487x over previous
//
#include <hip/hip_runtime.h>
#include <hip/hip_bf16.h>
#include <cstdint>
#include <math.h>

typedef __hip_bfloat16 bf16_t;
typedef __attribute__((ext_vector_type(8))) __bf16 bf16x8;
typedef __attribute__((ext_vector_type(4))) float f32x4;

static_assert(sizeof(bf16x8) == 16, "bf16x8 must be 4 VGPRs");

static constexpr int DD = 1024;   // D
static constexpr int HH = 4096;   // H = 4*D

// async global->LDS, 16B per lane.
#define GLD16(gp, lp)                                                                              \
  __builtin_amdgcn_global_load_lds(                                                                \
      (__attribute__((address_space(1))) void*)(uintptr_t)(gp),                                    \
      (__attribute__((address_space(3))) void*)(uint32_t)(uintptr_t)(lp), 16, 0, 0)

#if !__has_builtin(__builtin_amdgcn_exp2f)
#define __builtin_amdgcn_exp2f(x) exp2f(x)
#endif
#if !__has_builtin(__builtin_amdgcn_rcpf)
#define __builtin_amdgcn_rcpf(x) (1.0f / (x))
#endif

// Logistic approximation of exact-erf GELU. |err| <= ~0.02 on h, which reaches the
// output only through LayerNorm * tanh(0.01) -> ~1e-4 output impact. 5 VALU ops vs
// ~30 for erff (the erff epilogue was ~40% of GEMM2's cycles: VALUBusy 61%, MfmaUtil 22%).
__device__ __forceinline__ float fast_gelu(float u) {
  const float t = __builtin_amdgcn_exp2f(-2.4554089f * u);  // exp2(-1.702*log2(e)*u)
  return u * __builtin_amdgcn_rcpf(1.0f + t);
}

// ---------------- fp32 -> bf16 hi/lo split (for x) ----------------
__global__ __launch_bounds__(256) void k_split_x(const float* __restrict__ x,
                                                 bf16_t* __restrict__ xh,
                                                 bf16_t* __restrict__ xl, int n4) {
  int i = blockIdx.x * 256 + threadIdx.x;
  const int stride = gridDim.x * 256;
  for (; i < n4; i += stride) {
    const float4 v = reinterpret_cast<const float4*>(x)[i];
    float vv[4] = {v.x, v.y, v.z, v.w};
    union { bf16_t b[4]; short4 s; } H, L;
#pragma unroll
    for (int j = 0; j < 4; ++j) {
      H.b[j] = __float2bfloat16(vv[j]);
      L.b[j] = __float2bfloat16(vv[j] - __bfloat162float(H.b[j]));
    }
    reinterpret_cast<short4*>(xh)[i] = H.s;
    reinterpret_cast<short4*>(xl)[i] = L.s;
  }
}

// ---------------- transpose + convert weights: W[K][N] f32 -> WT[N][K] bf16 (optional lo) -----
template <bool SPLIT>
__global__ __launch_bounds__(256) void k_transpose(const float* __restrict__ W,
                                                   bf16_t* __restrict__ Th,
                                                   bf16_t* __restrict__ Tl, int K, int N) {
  __shared__ float tile[32][33];
  const int n0 = blockIdx.x * 32, k0 = blockIdx.y * 32;
  const int tx = threadIdx.x, ty = threadIdx.y;  // block (32,8)
#pragma unroll
  for (int r = 0; r < 4; ++r) {
    const int k = ty + r * 8;
    tile[k][tx] = W[(size_t)(k0 + k) * N + n0 + tx];
  }
  __syncthreads();
#pragma unroll
  for (int r = 0; r < 4; ++r) {
    const int n = ty + r * 8;
    const float v = tile[tx][n];
    const bf16_t h = __float2bfloat16(v);
    Th[(size_t)(n0 + n) * K + k0 + tx] = h;
    if (SPLIT) Tl[(size_t)(n0 + n) * K + k0 + tx] = __float2bfloat16(v - __bfloat162float(h));
  }
}

// ---------------- GEMM: C[M,N] = A[M,K] * B[K,N], B given pre-transposed BT[N][K] --------------
// EPI 1: write Cf=v (f32) and Cb=bf16(v)            (z for residual + z for GEMM2)
// EPI 2: write Cb=bf16(fast_gelu(v+bias[c]))        (h)
// EPI 3: write Cf=v+bias[c]                         (y)
// SPLIT: 3-pass hi/lo accumulation (A=Ah+Al, B=Bh+Bl; drop lo*lo term)
template <int EPI, bool SPLIT>
__global__ __launch_bounds__(256) void k_gemm(const bf16_t* __restrict__ Ah,
                                              const bf16_t* __restrict__ Al,
                                              const bf16_t* __restrict__ BTh,
                                              const bf16_t* __restrict__ BTl,
                                              const float* __restrict__ bias,
                                              float* __restrict__ Cf,
                                              bf16_t* __restrict__ Cb, int M, int N, int K) {
  constexpr int BM = 128, BN = 128, BK = 32;
  __shared__ __align__(16) bf16_t sAh[BM * BK];
  __shared__ __align__(16) bf16_t sBh[BN * BK];
  __shared__ __align__(16) bf16_t sAl[SPLIT ? BM * BK : 8];
  __shared__ __align__(16) bf16_t sBl[SPLIT ? BN * BK : 8];

  const int nbn = N / BN;
  const int nwg = gridDim.x;  // divisible by 8 for all our launches
  const int wg = blockIdx.x;
  const int cpx = nwg >> 3;
  const int swz = (wg & 7) * cpx + (wg >> 3);  // bijective XCD swizzle (nwg % 8 == 0)
  const int bm = swz / nbn, bn = swz % nbn;

  const int t = threadIdx.x;
  const int l = t & 63;
  const int w = t >> 6;
  const int wr = (w >> 1) * 64, wc = (w & 1) * 64;

  const size_t Abase = (size_t)bm * BM * K;
  const size_t Bbase = (size_t)bn * BN * K;

  // staging map: thread t covers row t>>2, k-elements (t&3)*8 (16B); second pass row+64.
  const int r0 = t >> 2, kc0 = (t & 3) * 8;
  const int r1 = r0 + 64;

  f32x4 acc[4][4] = {};
  const int lm = l & 15;
  const int kb8 = (l >> 4) * 8;

  const int nk = K / BK;
  for (int kt = 0; kt < nk; ++kt) {
    const size_t gk = (size_t)kt * BK;
    GLD16(Ah + Abase + (size_t)r0 * K + gk + kc0, &sAh[r0 * BK + kc0]);
    GLD16(Ah + Abase + (size_t)r1 * K + gk + kc0, &sAh[r1 * BK + kc0]);
    GLD16(BTh + Bbase + (size_t)r0 * K + gk + kc0, &sBh[r0 * BK + kc0]);
    GLD16(BTh + Bbase + (size_t)r1 * K + gk + kc0, &sBh[r1 * BK + kc0]);
    if (SPLIT) {
      GLD16(Al + Abase + (size_t)r0 * K + gk + kc0, &sAl[r0 * BK + kc0]);
      GLD16(Al + Abase + (size_t)r1 * K + gk + kc0, &sAl[r1 * BK + kc0]);
      GLD16(BTl + Bbase + (size_t)r0 * K + gk + kc0, &sBl[r0 * BK + kc0]);
      GLD16(BTl + Bbase + (size_t)r1 * K + gk + kc0, &sBl[r1 * BK + kc0]);
    }
    __syncthreads();

    bf16x8 a[4], b[4];
#pragma unroll
    for (int m = 0; m < 4; ++m)
      a[m] = *reinterpret_cast<const bf16x8*>(&sAh[(wr + m * 16 + lm) * BK + kb8]);
#pragma unroll
    for (int n = 0; n < 4; ++n)
      b[n] = *reinterpret_cast<const bf16x8*>(&sBh[(wc + n * 16 + lm) * BK + kb8]);
#pragma unroll
    for (int m = 0; m < 4; ++m)
#pragma unroll
      for (int n = 0; n < 4; ++n)
        acc[m][n] = __builtin_amdgcn_mfma_f32_16x16x32_bf16(a[m], b[n], acc[m][n], 0, 0, 0);

    if (SPLIT) {
      bf16x8 al_[4], bl_[4];
#pragma unroll
      for (int m = 0; m < 4; ++m)
        al_[m] = *reinterpret_cast<const bf16x8*>(&sAl[(wr + m * 16 + lm) * BK + kb8]);
#pragma unroll
      for (int n = 0; n < 4; ++n)
        bl_[n] = *reinterpret_cast<const bf16x8*>(&sBl[(wc + n * 16 + lm) * BK + kb8]);
#pragma unroll
      for (int m = 0; m < 4; ++m)
#pragma unroll
        for (int n = 0; n < 4; ++n) {
          acc[m][n] = __builtin_amdgcn_mfma_f32_16x16x32_bf16(a[m], bl_[n], acc[m][n], 0, 0, 0);
          acc[m][n] = __builtin_amdgcn_mfma_f32_16x16x32_bf16(al_[m], b[n], acc[m][n], 0, 0, 0);
        }
    }
    __syncthreads();
  }

  // C/D layout (m89-verified): col = lane&15, row = (lane>>4)*4 + j
  const int cr = (l >> 4) * 4;
#pragma unroll
  for (int m = 0; m < 4; ++m) {
#pragma unroll
    for (int n = 0; n < 4; ++n) {
      const int c = bn * BN + wc + n * 16 + lm;
      const float bc = (EPI == 2 || EPI == 3) ? bias[c] : 0.0f;
#pragma unroll
      for (int j = 0; j < 4; ++j) {
        const int r = bm * BM + wr + m * 16 + cr + j;
        const size_t idx = (size_t)r * N + c;
        const float v = acc[m][n][j];
        if (EPI == 1) {
          Cf[idx] = v;
          Cb[idx] = __float2bfloat16(v);
        } else if (EPI == 2) {
          Cb[idx] = __float2bfloat16(fast_gelu(v + bc));
        } else {
          Cf[idx] = v + bc;
        }
      }
    }
  }
}

// ---------------- LayerNorm(y) fused with residual: out = z + tanh(alpha)*ln ----------------
__global__ __launch_bounds__(256) void k_ln_res(const float* __restrict__ y,
                                                const float* __restrict__ z,
                                                const float* __restrict__ gamma,
                                                const float* __restrict__ beta,
                                                const float* __restrict__ alpha,
                                                float* __restrict__ out) {
  const int row = blockIdx.x;
  const int t = threadIdx.x;  // 256 threads * 4 floats = 1024 = D
  const float4 v = reinterpret_cast<const float4*>(y + (size_t)row * DD)[t];
  float s = v.x + v.y + v.z + v.w;
  float q = v.x * v.x + v.y * v.y + v.z * v.z + v.w * v.w;
#pragma unroll
  for (int m = 1; m < 64; m <<= 1) {
    s += __shfl_xor(s, m, 64);
    q += __shfl_xor(q, m, 64);
  }
  __shared__ float ss[4], sq[4];
  if ((t & 63) == 0) { ss[t >> 6] = s; sq[t >> 6] = q; }
  __syncthreads();
  s = ss[0] + ss[1] + ss[2] + ss[3];
  q = sq[0] + sq[1] + sq[2] + sq[3];
  const float mu = s * (1.0f / DD);
  const float var = fmaxf(q * (1.0f / DD) - mu * mu, 0.0f);
  const float rs = rsqrtf(var + 1e-5f);
  const float4 g = reinterpret_cast<const float4*>(gamma)[t];
  const float4 bb = reinterpret_cast<const float4*>(beta)[t];
  const float4 aa = reinterpret_cast<const float4*>(alpha)[t];
  const float4 zz = reinterpret_cast<const float4*>(z + (size_t)row * DD)[t];
  float4 o;
  o.x = zz.x + tanhf(aa.x) * ((v.x - mu) * rs * g.x + bb.x);
  o.y = zz.y + tanhf(aa.y) * ((v.y - mu) * rs * g.y + bb.y);
  o.z = zz.z + tanhf(aa.z) * ((v.z - mu) * rs * g.z + bb.z);
  o.w = zz.w + tanhf(aa.w) * ((v.w - mu) * rs * g.w + bb.w);
  reinterpret_cast<float4*>(out + (size_t)row * DD)[t] = o;
}

extern "C" void kernel_launch(void* const* d_in, const int* in_sizes, int n_in, void* d_out,
                              int out_size, void* d_ws, size_t ws_size, hipStream_t stream) {
  const float* x   = (const float*)d_in[0];
  const float* thQ = (const float*)d_in[1];
  const float* W1  = (const float*)d_in[2];
  const float* b1  = (const float*)d_in[3];
  const float* W2  = (const float*)d_in[4];
  const float* b2  = (const float*)d_in[5];
  const float* gam = (const float*)d_in[6];
  const float* bet = (const float*)d_in[7];
  const float* alp = (const float*)d_in[8];
  float* out = (float*)d_out;

  const int M = in_sizes[0] / DD;  // B*V*T = 8192

  char* ws = (char*)d_ws;
  size_t off = 0;
  auto take = [&](size_t bytes) -> char* {
    char* p = ws + off;
    off += (bytes + 255) & ~(size_t)255;
    return p;
  };
  bf16_t* xh  = (bf16_t*)take((size_t)M * DD * 2);
  bf16_t* xl  = (bf16_t*)take((size_t)M * DD * 2);
  bf16_t* qTh = (bf16_t*)take((size_t)DD * DD * 2);
  bf16_t* qTl = (bf16_t*)take((size_t)DD * DD * 2);
  bf16_t* w1T = (bf16_t*)take((size_t)DD * HH * 2);
  bf16_t* w2T = (bf16_t*)take((size_t)HH * DD * 2);
  float*  zf  = (float*)take((size_t)M * DD * 4);
  bf16_t* zb  = (bf16_t*)take((size_t)M * DD * 2);
  bf16_t* hb  = (bf16_t*)take((size_t)M * HH * 2);
  float*  yf  = (float*)take((size_t)M * DD * 4);

  // prep: conversions / transposes
  hipLaunchKernelGGL(k_split_x, dim3(2048), dim3(256), 0, stream, x, xh, xl, M * DD / 4);
  hipLaunchKernelGGL((k_transpose<true>), dim3(DD / 32, DD / 32), dim3(32, 8), 0, stream,
                     thQ, qTh, qTl, DD, DD);
  hipLaunchKernelGGL((k_transpose<false>), dim3(HH / 32, DD / 32), dim3(32, 8), 0, stream,
                     W1, w1T, (bf16_t*)nullptr, DD, HH);
  hipLaunchKernelGGL((k_transpose<false>), dim3(DD / 32, HH / 32), dim3(32, 8), 0, stream,
                     W2, w2T, (bf16_t*)nullptr, HH, DD);

  // z = x @ thetaQ  (split 3-pass for fp32-grade accuracy; z feeds output directly)
  hipLaunchKernelGGL((k_gemm<1, true>), dim3((M / 128) * (DD / 128)), dim3(256), 0, stream,
                     xh, xl, qTh, qTl, (const float*)nullptr, zf, zb, M, DD, DD);
  // h = gelu(z @ W1 + b1)   (bf16; error damped x100 by tanh(alpha) after LN)
  hipLaunchKernelGGL((k_gemm<2, false>), dim3((M / 128) * (HH / 128)), dim3(256), 0, stream,
                     zb, (const bf16_t*)nullptr, w1T, (const bf16_t*)nullptr, b1,
                     (float*)nullptr, hb, M, HH, DD);
  // y = h @ W2 + b2
  hipLaunchKernelGGL((k_gemm<3, false>), dim3((M / 128) * (DD / 128)), dim3(256), 0, stream,
                     hb, (const bf16_t*)nullptr, w2T, (const bf16_t*)nullptr, b2,
                     yf, (bf16_t*)nullptr, M, DD, HH);
  // out = z + tanh(alpha) * LayerNorm(y)
  hipLaunchKernelGGL(k_ln_res, dim3(M), dim3(256), 0, stream, yf, zf, gam, bet, alp, out);
}

// Round 4
// 389.794 us; speedup vs baseline: 1.0742x; 1.0243x over previous
//
#include <hip/hip_runtime.h>
#include <hip/hip_bf16.h>
#include <cstdint>
#include <math.h>

typedef __hip_bfloat16 bf16_t;
typedef __attribute__((ext_vector_type(8))) __bf16 bf16x8;
typedef __attribute__((ext_vector_type(4))) float f32x4;

static_assert(sizeof(bf16x8) == 16, "bf16x8 must be 4 VGPRs");

static constexpr int DD = 1024;   // D
static constexpr int HH = 4096;   // H = 4*D

// async global->LDS, 16B per lane.
#define GLD16(gp, lp)                                                                              \
  __builtin_amdgcn_global_load_lds(                                                                \
      (__attribute__((address_space(1))) void*)(uintptr_t)(gp),                                    \
      (__attribute__((address_space(3))) void*)(uint32_t)(uintptr_t)(lp), 16, 0, 0)

#if !__has_builtin(__builtin_amdgcn_exp2f)
#define __builtin_amdgcn_exp2f(x) exp2f(x)
#endif
#if !__has_builtin(__builtin_amdgcn_rcpf)
#define __builtin_amdgcn_rcpf(x) (1.0f / (x))
#endif

// Logistic GELU approx (|err|<=~0.02 on h; reaches output via LN * tanh(0.01) -> ~1e-4).
__device__ __forceinline__ float fast_gelu(float u) {
  const float t = __builtin_amdgcn_exp2f(-2.4554089f * u);
  return u * __builtin_amdgcn_rcpf(1.0f + t);
}

// ---------------- fp32 -> bf16 hi/lo split (for x) ----------------
__global__ __launch_bounds__(256) void k_split_x(const float* __restrict__ x,
                                                 bf16_t* __restrict__ xh,
                                                 bf16_t* __restrict__ xl, int n4) {
  int i = blockIdx.x * 256 + threadIdx.x;
  const int stride = gridDim.x * 256;
  for (; i < n4; i += stride) {
    const float4 v = reinterpret_cast<const float4*>(x)[i];
    float vv[4] = {v.x, v.y, v.z, v.w};
    union { bf16_t b[4]; short4 s; } H, L;
#pragma unroll
    for (int j = 0; j < 4; ++j) {
      H.b[j] = __float2bfloat16(vv[j]);
      L.b[j] = __float2bfloat16(vv[j] - __bfloat162float(H.b[j]));
    }
    reinterpret_cast<short4*>(xh)[i] = H.s;
    reinterpret_cast<short4*>(xl)[i] = L.s;
  }
}

// ---------------- transpose + convert weights: W[K][N] f32 -> WT[N][K] bf16 (optional lo) -----
template <bool SPLIT>
__global__ __launch_bounds__(256) void k_transpose(const float* __restrict__ W,
                                                   bf16_t* __restrict__ Th,
                                                   bf16_t* __restrict__ Tl, int K, int N) {
  __shared__ float tile[32][33];
  const int n0 = blockIdx.x * 32, k0 = blockIdx.y * 32;
  const int tx = threadIdx.x, ty = threadIdx.y;  // block (32,8)
#pragma unroll
  for (int r = 0; r < 4; ++r) {
    const int k = ty + r * 8;
    tile[k][tx] = W[(size_t)(k0 + k) * N + n0 + tx];
  }
  __syncthreads();
#pragma unroll
  for (int r = 0; r < 4; ++r) {
    const int n = ty + r * 8;
    const float v = tile[tx][n];
    const bf16_t h = __float2bfloat16(v);
    Th[(size_t)(n0 + n) * K + k0 + tx] = h;
    if (SPLIT) Tl[(size_t)(n0 + n) * K + k0 + tx] = __float2bfloat16(v - __bfloat162float(h));
  }
}

// ---------------- GEMM: C[M,N] = A[M,K-slice] * B[K-slice,N], B pre-transposed BT[N][LDK] -----
// EPI 1: Cf=v (f32) and Cb=bf16(v)                  (z)
// EPI 2: Cb=bf16(fast_gelu(v+bias[c]))              (h)
// EPI 3: Cf=v  raw partial (bias added in LN)       (y split-K slices, Cf += ks*M*N)
// BK=32: m97 staging map, unswizzled (proven; used by SPLIT GEMM1).
// BK=64: half the barriers; chunk-XOR swizzle (pre-swizzled global src, linear LDS dest,
//        swizzled ds_read) to avoid the 16-way row-stride-128B bank conflict.
template <int EPI, bool SPLIT, int BK>
__global__ __launch_bounds__(256) void k_gemm(const bf16_t* __restrict__ Ah,
                                              const bf16_t* __restrict__ Al,
                                              const bf16_t* __restrict__ BTh,
                                              const bf16_t* __restrict__ BTl,
                                              const float* __restrict__ bias,
                                              float* __restrict__ Cf,
                                              bf16_t* __restrict__ Cb,
                                              int M, int N, int K, int LDK) {
  static_assert(!SPLIT || BK == 32, "SPLIT path only implemented for BK=32");
  constexpr int BM = 128, BN = 128;
  __shared__ __align__(16) bf16_t sAh[BM * BK];
  __shared__ __align__(16) bf16_t sBh[BN * BK];
  __shared__ __align__(16) bf16_t sAl[SPLIT ? BM * BK : 8];
  __shared__ __align__(16) bf16_t sBl[SPLIT ? BN * BK : 8];

  const int nbn = N / BN;
  const int nwg = gridDim.x;  // divisible by 8 for all our launches
  const int wg = blockIdx.x;
  const int cpx = nwg >> 3;
  const int swz = (wg & 7) * cpx + (wg >> 3);  // bijective XCD swizzle (nwg % 8 == 0)
  const int bm = swz / nbn, bn = swz % nbn;

  const int ks = blockIdx.y;          // split-K slice
  const size_t k0 = (size_t)ks * K;
  Cf += (size_t)ks * M * N;

  const int t = threadIdx.x;
  const int l = t & 63;
  const int w = t >> 6;
  const int wr = (w >> 1) * 64, wc = (w & 1) * 64;

  const size_t Abase = (size_t)bm * BM * LDK + k0;
  const size_t Bbase = (size_t)bn * BN * LDK + k0;

  f32x4 acc[4][4] = {};
  const int lm = l & 15;
  const int l4 = l >> 4;

  const int nk = K / BK;
  for (int kt = 0; kt < nk; ++kt) {
    const size_t gk = (size_t)kt * BK;
    if (BK == 32) {
      const int r0 = t >> 2, kc0 = (t & 3) * 8;
      const int r1 = r0 + 64;
      GLD16(Ah + Abase + (size_t)r0 * LDK + gk + kc0, &sAh[r0 * BK + kc0]);
      GLD16(Ah + Abase + (size_t)r1 * LDK + gk + kc0, &sAh[r1 * BK + kc0]);
      GLD16(BTh + Bbase + (size_t)r0 * LDK + gk + kc0, &sBh[r0 * BK + kc0]);
      GLD16(BTh + Bbase + (size_t)r1 * LDK + gk + kc0, &sBh[r1 * BK + kc0]);
      if (SPLIT) {
        GLD16(Al + Abase + (size_t)r0 * LDK + gk + kc0, &sAl[r0 * BK + kc0]);
        GLD16(Al + Abase + (size_t)r1 * LDK + gk + kc0, &sAl[r1 * BK + kc0]);
        GLD16(BTl + Bbase + (size_t)r0 * LDK + gk + kc0, &sBl[r0 * BK + kc0]);
        GLD16(BTl + Bbase + (size_t)r1 * LDK + gk + kc0, &sBl[r1 * BK + kc0]);
      }
    } else {
      // BK=64: chunk c = t + 256p; row r = c>>3, chunk-in-row j = c&7.
      // Global source pre-swizzled: jg = j ^ (r&7); LDS dest linear at c*16B.
#pragma unroll
      for (int p = 0; p < 4; ++p) {
        const int c = t + 256 * p;
        const int r = c >> 3, j = c & 7;
        const int jg = (j ^ (r & 7)) * 8;
        GLD16(Ah + Abase + (size_t)r * LDK + gk + jg, &sAh[c * 8]);
      }
#pragma unroll
      for (int p = 0; p < 4; ++p) {
        const int c = t + 256 * p;
        const int r = c >> 3, j = c & 7;
        const int jg = (j ^ (r & 7)) * 8;
        GLD16(BTh + Bbase + (size_t)r * LDK + gk + jg, &sBh[c * 8]);
      }
    }
    __syncthreads();

    if (BK == 32) {
      const int kb8 = l4 * 8;
      bf16x8 a[4], b[4];
#pragma unroll
      for (int m = 0; m < 4; ++m)
        a[m] = *reinterpret_cast<const bf16x8*>(&sAh[(wr + m * 16 + lm) * BK + kb8]);
#pragma unroll
      for (int n = 0; n < 4; ++n)
        b[n] = *reinterpret_cast<const bf16x8*>(&sBh[(wc + n * 16 + lm) * BK + kb8]);
#pragma unroll
      for (int m = 0; m < 4; ++m)
#pragma unroll
        for (int n = 0; n < 4; ++n)
          acc[m][n] = __builtin_amdgcn_mfma_f32_16x16x32_bf16(a[m], b[n], acc[m][n], 0, 0, 0);

      if (SPLIT) {
        bf16x8 al_[4], bl_[4];
#pragma unroll
        for (int m = 0; m < 4; ++m)
          al_[m] = *reinterpret_cast<const bf16x8*>(&sAl[(wr + m * 16 + lm) * BK + kb8]);
#pragma unroll
        for (int n = 0; n < 4; ++n)
          bl_[n] = *reinterpret_cast<const bf16x8*>(&sBl[(wc + n * 16 + lm) * BK + kb8]);
#pragma unroll
        for (int m = 0; m < 4; ++m)
#pragma unroll
          for (int n = 0; n < 4; ++n) {
            acc[m][n] = __builtin_amdgcn_mfma_f32_16x16x32_bf16(a[m], bl_[n], acc[m][n], 0, 0, 0);
            acc[m][n] = __builtin_amdgcn_mfma_f32_16x16x32_bf16(al_[m], b[n], acc[m][n], 0, 0, 0);
          }
      }
    } else {
      // Two K=32 halves; swizzled read: row R, k-chunk q=(l>>4)+4h -> LDS chunk q^(R&7).
#pragma unroll
      for (int h = 0; h < 2; ++h) {
        bf16x8 a[4], b[4];
#pragma unroll
        for (int m = 0; m < 4; ++m) {
          const int R = wr + m * 16 + lm;
          const int q = (l4 + 4 * h) ^ (R & 7);
          a[m] = *reinterpret_cast<const bf16x8*>(&sAh[R * 64 + q * 8]);
        }
#pragma unroll
        for (int n = 0; n < 4; ++n) {
          const int R = wc + n * 16 + lm;
          const int q = (l4 + 4 * h) ^ (R & 7);
          b[n] = *reinterpret_cast<const bf16x8*>(&sBh[R * 64 + q * 8]);
        }
#pragma unroll
        for (int m = 0; m < 4; ++m)
#pragma unroll
          for (int n = 0; n < 4; ++n)
            acc[m][n] = __builtin_amdgcn_mfma_f32_16x16x32_bf16(a[m], b[n], acc[m][n], 0, 0, 0);
      }
    }
    __syncthreads();
  }

  // C/D layout (m89-verified): col = lane&15, row = (lane>>4)*4 + j
  const int cr = l4 * 4;
#pragma unroll
  for (int m = 0; m < 4; ++m) {
#pragma unroll
    for (int n = 0; n < 4; ++n) {
      const int c = bn * BN + wc + n * 16 + lm;
      const float bc = (EPI == 2) ? bias[c] : 0.0f;
#pragma unroll
      for (int j = 0; j < 4; ++j) {
        const int r = bm * BM + wr + m * 16 + cr + j;
        const size_t idx = (size_t)r * N + c;
        const float v = acc[m][n][j];
        if (EPI == 1) {
          Cf[idx] = v;
          Cb[idx] = __float2bfloat16(v);
        } else if (EPI == 2) {
          Cb[idx] = __float2bfloat16(fast_gelu(v + bc));
        } else {
          Cf[idx] = v;
        }
      }
    }
  }
}

// ---------------- LN(y0+y1+b2) fused with residual: out = z + tanh(alpha)*ln ----------------
__global__ __launch_bounds__(256) void k_ln_res(const float* __restrict__ y0,
                                                const float* __restrict__ y1,
                                                const float* __restrict__ b2,
                                                const float* __restrict__ z,
                                                const float* __restrict__ gamma,
                                                const float* __restrict__ beta,
                                                const float* __restrict__ alpha,
                                                float* __restrict__ out) {
  const int row = blockIdx.x;
  const int t = threadIdx.x;  // 256 threads * 4 floats = 1024 = D
  const float4 va = reinterpret_cast<const float4*>(y0 + (size_t)row * DD)[t];
  const float4 vb = reinterpret_cast<const float4*>(y1 + (size_t)row * DD)[t];
  const float4 bc = reinterpret_cast<const float4*>(b2)[t];
  float4 v;
  v.x = va.x + vb.x + bc.x; v.y = va.y + vb.y + bc.y;
  v.z = va.z + vb.z + bc.z; v.w = va.w + vb.w + bc.w;
  float s = v.x + v.y + v.z + v.w;
  float q = v.x * v.x + v.y * v.y + v.z * v.z + v.w * v.w;
#pragma unroll
  for (int m = 1; m < 64; m <<= 1) {
    s += __shfl_xor(s, m, 64);
    q += __shfl_xor(q, m, 64);
  }
  __shared__ float ss[4], sq[4];
  if ((t & 63) == 0) { ss[t >> 6] = s; sq[t >> 6] = q; }
  __syncthreads();
  s = ss[0] + ss[1] + ss[2] + ss[3];
  q = sq[0] + sq[1] + sq[2] + sq[3];
  const float mu = s * (1.0f / DD);
  const float var = fmaxf(q * (1.0f / DD) - mu * mu, 0.0f);
  const float rs = rsqrtf(var + 1e-5f);
  const float4 g = reinterpret_cast<const float4*>(gamma)[t];
  const float4 bb = reinterpret_cast<const float4*>(beta)[t];
  const float4 aa = reinterpret_cast<const float4*>(alpha)[t];
  const float4 zz = reinterpret_cast<const float4*>(z + (size_t)row * DD)[t];
  float4 o;
  o.x = zz.x + tanhf(aa.x) * ((v.x - mu) * rs * g.x + bb.x);
  o.y = zz.y + tanhf(aa.y) * ((v.y - mu) * rs * g.y + bb.y);
  o.z = zz.z + tanhf(aa.z) * ((v.z - mu) * rs * g.z + bb.z);
  o.w = zz.w + tanhf(aa.w) * ((v.w - mu) * rs * g.w + bb.w);
  reinterpret_cast<float4*>(out + (size_t)row * DD)[t] = o;
}

extern "C" void kernel_launch(void* const* d_in, const int* in_sizes, int n_in, void* d_out,
                              int out_size, void* d_ws, size_t ws_size, hipStream_t stream) {
  const float* x   = (const float*)d_in[0];
  const float* thQ = (const float*)d_in[1];
  const float* W1  = (const float*)d_in[2];
  const float* b1  = (const float*)d_in[3];
  const float* W2  = (const float*)d_in[4];
  const float* b2  = (const float*)d_in[5];
  const float* gam = (const float*)d_in[6];
  const float* bet = (const float*)d_in[7];
  const float* alp = (const float*)d_in[8];
  float* out = (float*)d_out;

  const int M = in_sizes[0] / DD;  // B*V*T = 8192

  char* ws = (char*)d_ws;
  size_t off = 0;
  auto take = [&](size_t bytes) -> char* {
    char* p = ws + off;
    off += (bytes + 255) & ~(size_t)255;
    return p;
  };
  bf16_t* xh  = (bf16_t*)take((size_t)M * DD * 2);
  bf16_t* xl  = (bf16_t*)take((size_t)M * DD * 2);
  bf16_t* qTh = (bf16_t*)take((size_t)DD * DD * 2);
  bf16_t* qTl = (bf16_t*)take((size_t)DD * DD * 2);
  bf16_t* w1T = (bf16_t*)take((size_t)DD * HH * 2);
  bf16_t* w2T = (bf16_t*)take((size_t)HH * DD * 2);
  float*  zf  = (float*)take((size_t)M * DD * 4);
  bf16_t* zb  = (bf16_t*)take((size_t)M * DD * 2);
  bf16_t* hb  = (bf16_t*)take((size_t)M * HH * 2);
  float*  yf  = (float*)take((size_t)M * DD * 4 * 2);  // 2 split-K partials

  // prep: conversions / transposes
  hipLaunchKernelGGL(k_split_x, dim3(2048), dim3(256), 0, stream, x, xh, xl, M * DD / 4);
  hipLaunchKernelGGL((k_transpose<true>), dim3(DD / 32, DD / 32), dim3(32, 8), 0, stream,
                     thQ, qTh, qTl, DD, DD);
  hipLaunchKernelGGL((k_transpose<false>), dim3(HH / 32, DD / 32), dim3(32, 8), 0, stream,
                     W1, w1T, (bf16_t*)nullptr, DD, HH);
  hipLaunchKernelGGL((k_transpose<false>), dim3(DD / 32, HH / 32), dim3(32, 8), 0, stream,
                     W2, w2T, (bf16_t*)nullptr, HH, DD);

  // z = x @ thetaQ  (split 3-pass, BK=32 proven path)
  hipLaunchKernelGGL((k_gemm<1, true, 32>), dim3((M / 128) * (DD / 128)), dim3(256), 0, stream,
                     xh, xl, qTh, qTl, (const float*)nullptr, zf, zb, M, DD, DD, DD);
  // h = gelu(z @ W1 + b1)   (BK=64, swizzled)
  hipLaunchKernelGGL((k_gemm<2, false, 64>), dim3((M / 128) * (HH / 128)), dim3(256), 0, stream,
                     zb, (const bf16_t*)nullptr, w1T, (const bf16_t*)nullptr, b1,
                     (float*)nullptr, hb, M, HH, DD, DD);
  // y = h @ W2 (split-K=2 raw partials; bias in LN)
  hipLaunchKernelGGL((k_gemm<3, false, 64>), dim3((M / 128) * (DD / 128), 2), dim3(256), 0,
                     stream, hb, (const bf16_t*)nullptr, w2T, (const bf16_t*)nullptr,
                     (const float*)nullptr, yf, (bf16_t*)nullptr, M, DD, HH / 2, HH);
  // out = z + tanh(alpha) * LayerNorm(y0+y1+b2)
  hipLaunchKernelGGL(k_ln_res, dim3(M), dim3(256), 0, stream,
                     yf, yf + (size_t)M * DD, b2, zf, gam, bet, alp, out);
}

// Round 8
// 363.958 us; speedup vs baseline: 1.1504x; 1.0710x over previous
//
#include <hip/hip_runtime.h>
#include <hip/hip_bf16.h>
#include <cstdint>
#include <math.h>

typedef __hip_bfloat16 bf16_t;
typedef __attribute__((ext_vector_type(8))) __bf16 bf16x8;
typedef __attribute__((ext_vector_type(4))) float f32x4;

static_assert(sizeof(bf16x8) == 16, "bf16x8 must be 4 VGPRs");

static constexpr int DD = 1024;   // D
static constexpr int HH = 4096;   // H = 4*D

// async global->LDS, 16B per lane.
#define GLD16(gp, lp)                                                                              \
  __builtin_amdgcn_global_load_lds(                                                                \
      (__attribute__((address_space(1))) void*)(uintptr_t)(gp),                                    \
      (__attribute__((address_space(3))) void*)(uint32_t)(uintptr_t)(lp), 16, 0, 0)

#if !__has_builtin(__builtin_amdgcn_exp2f)
#define __builtin_amdgcn_exp2f(x) exp2f(x)
#endif
#if !__has_builtin(__builtin_amdgcn_rcpf)
#define __builtin_amdgcn_rcpf(x) (1.0f / (x))
#endif

// Logistic GELU approx (|err|<=~0.02 on h; reaches output via LN * tanh(0.01) -> ~1e-4).
__device__ __forceinline__ float fast_gelu(float u) {
  const float t = __builtin_amdgcn_exp2f(-2.4554089f * u);
  return u * __builtin_amdgcn_rcpf(1.0f + t);
}

// ---------------- fp32 -> bf16 hi/lo split (for x) ----------------
__global__ __launch_bounds__(256) void k_split_x(const float* __restrict__ x,
                                                 bf16_t* __restrict__ xh,
                                                 bf16_t* __restrict__ xl, int n4) {
  int i = blockIdx.x * 256 + threadIdx.x;
  const int stride = gridDim.x * 256;
  for (; i < n4; i += stride) {
    const float4 v = reinterpret_cast<const float4*>(x)[i];
    float vv[4] = {v.x, v.y, v.z, v.w};
    union { bf16_t b[4]; short4 s; } H, L;
#pragma unroll
    for (int j = 0; j < 4; ++j) {
      H.b[j] = __float2bfloat16(vv[j]);
      L.b[j] = __float2bfloat16(vv[j] - __bfloat162float(H.b[j]));
    }
    reinterpret_cast<short4*>(xh)[i] = H.s;
    reinterpret_cast<short4*>(xl)[i] = L.s;
  }
}

// ---------------- transpose + convert weights: W[K][N] f32 -> WT[N][K] bf16 (optional lo) -----
template <bool SPLIT>
__global__ __launch_bounds__(256) void k_transpose(const float* __restrict__ W,
                                                   bf16_t* __restrict__ Th,
                                                   bf16_t* __restrict__ Tl, int K, int N) {
  __shared__ float tile[32][33];
  const int n0 = blockIdx.x * 32, k0 = blockIdx.y * 32;
  const int tx = threadIdx.x, ty = threadIdx.y;  // block (32,8)
#pragma unroll
  for (int r = 0; r < 4; ++r) {
    const int k = ty + r * 8;
    tile[k][tx] = W[(size_t)(k0 + k) * N + n0 + tx];
  }
  __syncthreads();
#pragma unroll
  for (int r = 0; r < 4; ++r) {
    const int n = ty + r * 8;
    const float v = tile[tx][n];
    const bf16_t h = __float2bfloat16(v);
    Th[(size_t)(n0 + n) * K + k0 + tx] = h;
    if (SPLIT) Tl[(size_t)(n0 + n) * K + k0 + tx] = __float2bfloat16(v - __bfloat162float(h));
  }
}

// ---------------- GEMM1 (SPLIT, BK=32, proven m97-style drain loop) ------------------------
__global__ __launch_bounds__(256) void k_gemm_split(const bf16_t* __restrict__ Ah,
                                                    const bf16_t* __restrict__ Al,
                                                    const bf16_t* __restrict__ BTh,
                                                    const bf16_t* __restrict__ BTl,
                                                    float* __restrict__ Cf,
                                                    bf16_t* __restrict__ Cb,
                                                    int M, int N, int K) {
  constexpr int BM = 128, BN = 128, BK = 32;
  __shared__ __align__(16) bf16_t sAh[BM * BK];
  __shared__ __align__(16) bf16_t sBh[BN * BK];
  __shared__ __align__(16) bf16_t sAl[BM * BK];
  __shared__ __align__(16) bf16_t sBl[BN * BK];

  const int nbn = N / BN;
  const int nwg = gridDim.x;
  const int wg = blockIdx.x;
  const int cpx = nwg >> 3;
  const int swz = (wg & 7) * cpx + (wg >> 3);
  const int bm = swz / nbn, bn = swz % nbn;

  const int t = threadIdx.x;
  const int l = t & 63;
  const int w = t >> 6;
  const int wr = (w >> 1) * 64, wc = (w & 1) * 64;

  const size_t Abase = (size_t)bm * BM * K;
  const size_t Bbase = (size_t)bn * BN * K;

  const int r0 = t >> 2, kc0 = (t & 3) * 8;
  const int r1 = r0 + 64;

  f32x4 acc[4][4] = {};
  const int lm = l & 15;
  const int l4 = l >> 4;
  const int kb8 = l4 * 8;

  const int nk = K / BK;
  for (int kt = 0; kt < nk; ++kt) {
    const size_t gk = (size_t)kt * BK;
    GLD16(Ah + Abase + (size_t)r0 * K + gk + kc0, &sAh[r0 * BK + kc0]);
    GLD16(Ah + Abase + (size_t)r1 * K + gk + kc0, &sAh[r1 * BK + kc0]);
    GLD16(BTh + Bbase + (size_t)r0 * K + gk + kc0, &sBh[r0 * BK + kc0]);
    GLD16(BTh + Bbase + (size_t)r1 * K + gk + kc0, &sBh[r1 * BK + kc0]);
    GLD16(Al + Abase + (size_t)r0 * K + gk + kc0, &sAl[r0 * BK + kc0]);
    GLD16(Al + Abase + (size_t)r1 * K + gk + kc0, &sAl[r1 * BK + kc0]);
    GLD16(BTl + Bbase + (size_t)r0 * K + gk + kc0, &sBl[r0 * BK + kc0]);
    GLD16(BTl + Bbase + (size_t)r1 * K + gk + kc0, &sBl[r1 * BK + kc0]);
    __syncthreads();

    bf16x8 a[4], b[4];
#pragma unroll
    for (int m = 0; m < 4; ++m)
      a[m] = *reinterpret_cast<const bf16x8*>(&sAh[(wr + m * 16 + lm) * BK + kb8]);
#pragma unroll
    for (int n = 0; n < 4; ++n)
      b[n] = *reinterpret_cast<const bf16x8*>(&sBh[(wc + n * 16 + lm) * BK + kb8]);
#pragma unroll
    for (int m = 0; m < 4; ++m)
#pragma unroll
      for (int n = 0; n < 4; ++n)
        acc[m][n] = __builtin_amdgcn_mfma_f32_16x16x32_bf16(a[m], b[n], acc[m][n], 0, 0, 0);

    {
      bf16x8 al_[4], bl_[4];
#pragma unroll
      for (int m = 0; m < 4; ++m)
        al_[m] = *reinterpret_cast<const bf16x8*>(&sAl[(wr + m * 16 + lm) * BK + kb8]);
#pragma unroll
      for (int n = 0; n < 4; ++n)
        bl_[n] = *reinterpret_cast<const bf16x8*>(&sBl[(wc + n * 16 + lm) * BK + kb8]);
#pragma unroll
      for (int m = 0; m < 4; ++m)
#pragma unroll
        for (int n = 0; n < 4; ++n) {
          acc[m][n] = __builtin_amdgcn_mfma_f32_16x16x32_bf16(a[m], bl_[n], acc[m][n], 0, 0, 0);
          acc[m][n] = __builtin_amdgcn_mfma_f32_16x16x32_bf16(al_[m], b[n], acc[m][n], 0, 0, 0);
        }
    }
    __syncthreads();
  }

  const int cr = l4 * 4;
#pragma unroll
  for (int m = 0; m < 4; ++m) {
#pragma unroll
    for (int n = 0; n < 4; ++n) {
      const int c = bn * BN + wc + n * 16 + lm;
#pragma unroll
      for (int j = 0; j < 4; ++j) {
        const int r = bm * BM + wr + m * 16 + cr + j;
        const size_t idx = (size_t)r * N + c;
        const float v = acc[m][n][j];
        Cf[idx] = v;
        Cb[idx] = __float2bfloat16(v);
      }
    }
  }
}

// ---------------- GEMM2/3: BK=64, chunk-XOR swizzle, depth-2 counted-vmcnt pipeline ----------
// EPI 2: Cb=bf16(fast_gelu(v+bias[c]))              (h)
// EPI 3: Cf=v raw partial (bias in LN)              (y split-K, Cf += ks*M*N)
// Schedule per K-tile: vmcnt(8) [tail:0] -> s_barrier -> compute buf[kt&1] -> s_barrier ->
// stage tile kt+2 into buf[kt&1]. Loads for the next tile are never drained (T4).
template <int EPI>
__global__ __launch_bounds__(256) void k_gemm_pipe(const bf16_t* __restrict__ A,
                                                   const bf16_t* __restrict__ BT,
                                                   const float* __restrict__ bias,
                                                   float* __restrict__ Cf,
                                                   bf16_t* __restrict__ Cb,
                                                   int M, int N, int K, int LDK) {
  constexpr int BM = 128, BN = 128, BK = 64;
  __shared__ __align__(16) bf16_t sA[2][BM * BK];
  __shared__ __align__(16) bf16_t sB[2][BN * BK];

  const int nbn = N / BN;
  const int nwg = gridDim.x;
  const int wg = blockIdx.x;
  const int cpx = nwg >> 3;
  const int swz = (wg & 7) * cpx + (wg >> 3);  // bijective XCD swizzle (nwg % 8 == 0)
  const int bm = swz / nbn, bn = swz % nbn;

  const int ks = blockIdx.y;  // split-K slice
  const size_t k0 = (size_t)ks * K;
  Cf += (size_t)ks * M * N;

  const int t = threadIdx.x;
  const int l = t & 63;
  const int w = t >> 6;
  const int wr = (w >> 1) * 64, wc = (w & 1) * 64;

  const size_t Abase = (size_t)bm * BM * LDK + k0;
  const size_t Bbase = (size_t)bn * BN * LDK + k0;

  const int lm = l & 15;
  const int l4 = l >> 4;

  // staging: chunk c = t + 256p; row r=c>>3, 16B-chunk j=c&7; global pre-swizzled j^(r&7),
  // LDS dest linear (wave-uniform base + lane*16) -> GLD-compatible; proven conflict-free.
  auto stage = [&](int kt, int pb) {
    const size_t gk = (size_t)kt * BK;
#pragma unroll
    for (int p = 0; p < 4; ++p) {
      const int c = t + 256 * p;
      const int r = c >> 3, j = c & 7;
      const int jg = (j ^ (r & 7)) * 8;
      GLD16(A + Abase + (size_t)r * LDK + gk + jg, &sA[pb][c * 8]);
    }
#pragma unroll
    for (int p = 0; p < 4; ++p) {
      const int c = t + 256 * p;
      const int r = c >> 3, j = c & 7;
      const int jg = (j ^ (r & 7)) * 8;
      GLD16(BT + Bbase + (size_t)r * LDK + gk + jg, &sB[pb][c * 8]);
    }
  };

  f32x4 acc[4][4] = {};
  const int nk = K / BK;

  stage(0, 0);
  stage(1, 1);
  for (int kt = 0; kt < nk; ++kt) {
    const int pb = kt & 1;
    if (kt + 1 < nk) {
      asm volatile("s_waitcnt vmcnt(8)" ::: "memory");   // tile kt done; kt+1 stays in flight
    } else {
      asm volatile("s_waitcnt vmcnt(0)" ::: "memory");   // tail drain
    }
    __builtin_amdgcn_s_barrier();                        // all threads' tile-kt loads landed
    __builtin_amdgcn_sched_barrier(0);

#pragma unroll
    for (int h = 0; h < 2; ++h) {
      bf16x8 a[4], b[4];
#pragma unroll
      for (int m = 0; m < 4; ++m) {
        const int R = wr + m * 16 + lm;
        const int q = (l4 + 4 * h) ^ (R & 7);
        a[m] = *reinterpret_cast<const bf16x8*>(&sA[pb][R * 64 + q * 8]);
      }
#pragma unroll
      for (int n = 0; n < 4; ++n) {
        const int R = wc + n * 16 + lm;
        const int q = (l4 + 4 * h) ^ (R & 7);
        b[n] = *reinterpret_cast<const bf16x8*>(&sB[pb][R * 64 + q * 8]);
      }
#pragma unroll
      for (int m = 0; m < 4; ++m)
#pragma unroll
        for (int n = 0; n < 4; ++n)
          acc[m][n] = __builtin_amdgcn_mfma_f32_16x16x32_bf16(a[m], b[n], acc[m][n], 0, 0, 0);
    }

    __builtin_amdgcn_sched_barrier(0);
    __builtin_amdgcn_s_barrier();                        // all waves done reading buf[pb]
    if (kt + 2 < nk) stage(kt + 2, pb);                  // restage same buffer, 2 tiles ahead
  }

  const int cr = l4 * 4;
#pragma unroll
  for (int m = 0; m < 4; ++m) {
#pragma unroll
    for (int n = 0; n < 4; ++n) {
      const int c = bn * BN + wc + n * 16 + lm;
      const float bc = (EPI == 2) ? bias[c] : 0.0f;
#pragma unroll
      for (int j = 0; j < 4; ++j) {
        const int r = bm * BM + wr + m * 16 + cr + j;
        const size_t idx = (size_t)r * N + c;
        const float v = acc[m][n][j];
        if (EPI == 2) {
          Cb[idx] = __float2bfloat16(fast_gelu(v + bc));
        } else {
          Cf[idx] = v;
        }
      }
    }
  }
}

// ---------------- LN(y0+y1+b2) fused with residual: out = z + tanh(alpha)*ln ----------------
__global__ __launch_bounds__(256) void k_ln_res(const float* __restrict__ y0,
                                                const float* __restrict__ y1,
                                                const float* __restrict__ b2,
                                                const float* __restrict__ z,
                                                const float* __restrict__ gamma,
                                                const float* __restrict__ beta,
                                                const float* __restrict__ alpha,
                                                float* __restrict__ out) {
  const int row = blockIdx.x;
  const int t = threadIdx.x;  // 256 threads * 4 floats = 1024 = D
  const float4 va = reinterpret_cast<const float4*>(y0 + (size_t)row * DD)[t];
  const float4 vb = reinterpret_cast<const float4*>(y1 + (size_t)row * DD)[t];
  const float4 bc = reinterpret_cast<const float4*>(b2)[t];
  float4 v;
  v.x = va.x + vb.x + bc.x; v.y = va.y + vb.y + bc.y;
  v.z = va.z + vb.z + bc.z; v.w = va.w + vb.w + bc.w;
  float s = v.x + v.y + v.z + v.w;
  float q = v.x * v.x + v.y * v.y + v.z * v.z + v.w * v.w;
#pragma unroll
  for (int m = 1; m < 64; m <<= 1) {
    s += __shfl_xor(s, m, 64);
    q += __shfl_xor(q, m, 64);
  }
  __shared__ float ss[4], sq[4];
  if ((t & 63) == 0) { ss[t >> 6] = s; sq[t >> 6] = q; }
  __syncthreads();
  s = ss[0] + ss[1] + ss[2] + ss[3];
  q = sq[0] + sq[1] + sq[2] + sq[3];
  const float mu = s * (1.0f / DD);
  const float var = fmaxf(q * (1.0f / DD) - mu * mu, 0.0f);
  const float rs = rsqrtf(var + 1e-5f);
  const float4 g = reinterpret_cast<const float4*>(gamma)[t];
  const float4 bb = reinterpret_cast<const float4*>(beta)[t];
  const float4 aa = reinterpret_cast<const float4*>(alpha)[t];
  const float4 zz = reinterpret_cast<const float4*>(z + (size_t)row * DD)[t];
  float4 o;
  o.x = zz.x + tanhf(aa.x) * ((v.x - mu) * rs * g.x + bb.x);
  o.y = zz.y + tanhf(aa.y) * ((v.y - mu) * rs * g.y + bb.y);
  o.z = zz.z + tanhf(aa.z) * ((v.z - mu) * rs * g.z + bb.z);
  o.w = zz.w + tanhf(aa.w) * ((v.w - mu) * rs * g.w + bb.w);
  reinterpret_cast<float4*>(out + (size_t)row * DD)[t] = o;
}

extern "C" void kernel_launch(void* const* d_in, const int* in_sizes, int n_in, void* d_out,
                              int out_size, void* d_ws, size_t ws_size, hipStream_t stream) {
  const float* x   = (const float*)d_in[0];
  const float* thQ = (const float*)d_in[1];
  const float* W1  = (const float*)d_in[2];
  const float* b1  = (const float*)d_in[3];
  const float* W2  = (const float*)d_in[4];
  const float* b2  = (const float*)d_in[5];
  const float* gam = (const float*)d_in[6];
  const float* bet = (const float*)d_in[7];
  const float* alp = (const float*)d_in[8];
  float* out = (float*)d_out;

  const int M = in_sizes[0] / DD;  // B*V*T = 8192

  char* ws = (char*)d_ws;
  size_t off = 0;
  auto take = [&](size_t bytes) -> char* {
    char* p = ws + off;
    off += (bytes + 255) & ~(size_t)255;
    return p;
  };
  bf16_t* xh  = (bf16_t*)take((size_t)M * DD * 2);
  bf16_t* xl  = (bf16_t*)take((size_t)M * DD * 2);
  bf16_t* qTh = (bf16_t*)take((size_t)DD * DD * 2);
  bf16_t* qTl = (bf16_t*)take((size_t)DD * DD * 2);
  bf16_t* w1T = (bf16_t*)take((size_t)DD * HH * 2);
  bf16_t* w2T = (bf16_t*)take((size_t)HH * DD * 2);
  float*  zf  = (float*)take((size_t)M * DD * 4);
  bf16_t* zb  = (bf16_t*)take((size_t)M * DD * 2);
  bf16_t* hb  = (bf16_t*)take((size_t)M * HH * 2);
  float*  yf  = (float*)take((size_t)M * DD * 4 * 2);  // 2 split-K partials

  // prep: conversions / transposes
  hipLaunchKernelGGL(k_split_x, dim3(2048), dim3(256), 0, stream, x, xh, xl, M * DD / 4);
  hipLaunchKernelGGL((k_transpose<true>), dim3(DD / 32, DD / 32), dim3(32, 8), 0, stream,
                     thQ, qTh, qTl, DD, DD);
  hipLaunchKernelGGL((k_transpose<false>), dim3(HH / 32, DD / 32), dim3(32, 8), 0, stream,
                     W1, w1T, (bf16_t*)nullptr, DD, HH);
  hipLaunchKernelGGL((k_transpose<false>), dim3(DD / 32, HH / 32), dim3(32, 8), 0, stream,
                     W2, w2T, (bf16_t*)nullptr, HH, DD);

  // z = x @ thetaQ  (split 3-pass, BK=32 proven drain loop)
  hipLaunchKernelGGL(k_gemm_split, dim3((M / 128) * (DD / 128)), dim3(256), 0, stream,
                     xh, xl, qTh, qTl, zf, zb, M, DD, DD);
  // h = gelu(z @ W1 + b1)   (BK=64, swizzled, counted-vmcnt pipeline)
  hipLaunchKernelGGL((k_gemm_pipe<2>), dim3((M / 128) * (HH / 128)), dim3(256), 0, stream,
                     zb, w1T, b1, (float*)nullptr, hb, M, HH, DD, DD);
  // y = h @ W2 (split-K=2 raw partials; bias in LN)
  hipLaunchKernelGGL((k_gemm_pipe<3>), dim3((M / 128) * (DD / 128), 2), dim3(256), 0, stream,
                     hb, w2T, (const float*)nullptr, yf, (bf16_t*)nullptr, M, DD, HH / 2, HH);
  // out = z + tanh(alpha) * LayerNorm(y0+y1+b2)
  hipLaunchKernelGGL(k_ln_res, dim3(M), dim3(256), 0, stream,
                     yf, yf + (size_t)M * DD, b2, zf, gam, bet, alp, out);
}

// Round 9
// 360.783 us; speedup vs baseline: 1.1606x; 1.0088x over previous
//
#include <hip/hip_runtime.h>
#include <hip/hip_bf16.h>
#include <cstdint>
#include <math.h>

typedef __hip_bfloat16 bf16_t;
typedef __attribute__((ext_vector_type(8))) __bf16 bf16x8;
typedef __attribute__((ext_vector_type(4))) float f32x4;

static_assert(sizeof(bf16x8) == 16, "bf16x8 must be 4 VGPRs");

static constexpr int DD = 1024;   // D
static constexpr int HH = 4096;   // H = 4*D

// async global->LDS, 16B per lane.
#define GLD16(gp, lp)                                                                              \
  __builtin_amdgcn_global_load_lds(                                                                \
      (__attribute__((address_space(1))) void*)(uintptr_t)(gp),                                    \
      (__attribute__((address_space(3))) void*)(uint32_t)(uintptr_t)(lp), 16, 0, 0)

#if !__has_builtin(__builtin_amdgcn_exp2f)
#define __builtin_amdgcn_exp2f(x) exp2f(x)
#endif
#if !__has_builtin(__builtin_amdgcn_rcpf)
#define __builtin_amdgcn_rcpf(x) (1.0f / (x))
#endif

// Logistic GELU approx (|err|<=~0.02 on h; reaches output via LN * tanh(0.01) -> ~1e-4).
__device__ __forceinline__ float fast_gelu(float u) {
  const float t = __builtin_amdgcn_exp2f(-2.4554089f * u);
  return u * __builtin_amdgcn_rcpf(1.0f + t);
}

// ---------------- fp32 -> bf16 hi/lo split (for x) ----------------
__global__ __launch_bounds__(256) void k_split_x(const float* __restrict__ x,
                                                 bf16_t* __restrict__ xh,
                                                 bf16_t* __restrict__ xl, int n4) {
  int i = blockIdx.x * 256 + threadIdx.x;
  const int stride = gridDim.x * 256;
  for (; i < n4; i += stride) {
    const float4 v = reinterpret_cast<const float4*>(x)[i];
    float vv[4] = {v.x, v.y, v.z, v.w};
    union { bf16_t b[4]; short4 s; } H, L;
#pragma unroll
    for (int j = 0; j < 4; ++j) {
      H.b[j] = __float2bfloat16(vv[j]);
      L.b[j] = __float2bfloat16(vv[j] - __bfloat162float(H.b[j]));
    }
    reinterpret_cast<short4*>(xh)[i] = H.s;
    reinterpret_cast<short4*>(xl)[i] = L.s;
  }
}

// ---------------- transpose + convert weights: W[K][N] f32 -> WT[N][K] bf16 (optional lo) -----
template <bool SPLIT>
__global__ __launch_bounds__(256) void k_transpose(const float* __restrict__ W,
                                                   bf16_t* __restrict__ Th,
                                                   bf16_t* __restrict__ Tl, int K, int N) {
  __shared__ float tile[32][33];
  const int n0 = blockIdx.x * 32, k0 = blockIdx.y * 32;
  const int tx = threadIdx.x, ty = threadIdx.y;  // block (32,8)
#pragma unroll
  for (int r = 0; r < 4; ++r) {
    const int k = ty + r * 8;
    tile[k][tx] = W[(size_t)(k0 + k) * N + n0 + tx];
  }
  __syncthreads();
#pragma unroll
  for (int r = 0; r < 4; ++r) {
    const int n = ty + r * 8;
    const float v = tile[tx][n];
    const bf16_t h = __float2bfloat16(v);
    Th[(size_t)(n0 + n) * K + k0 + tx] = h;
    if (SPLIT) Tl[(size_t)(n0 + n) * K + k0 + tx] = __float2bfloat16(v - __bfloat162float(h));
  }
}

// ---------------- GEMM1 (SPLIT, BK=32, proven m97-style drain loop) ------------------------
__global__ __launch_bounds__(256) void k_gemm_split(const bf16_t* __restrict__ Ah,
                                                    const bf16_t* __restrict__ Al,
                                                    const bf16_t* __restrict__ BTh,
                                                    const bf16_t* __restrict__ BTl,
                                                    float* __restrict__ Cf,
                                                    bf16_t* __restrict__ Cb,
                                                    int M, int N, int K) {
  constexpr int BM = 128, BN = 128, BK = 32;
  __shared__ __align__(16) bf16_t sAh[BM * BK];
  __shared__ __align__(16) bf16_t sBh[BN * BK];
  __shared__ __align__(16) bf16_t sAl[BM * BK];
  __shared__ __align__(16) bf16_t sBl[BN * BK];

  const int nbn = N / BN;
  const int nwg = gridDim.x;
  const int wg = blockIdx.x;
  const int cpx = nwg >> 3;
  const int swz = (wg & 7) * cpx + (wg >> 3);
  const int bm = swz / nbn, bn = swz % nbn;

  const int t = threadIdx.x;
  const int l = t & 63;
  const int w = t >> 6;
  const int wr = (w >> 1) * 64, wc = (w & 1) * 64;

  const size_t Abase = (size_t)bm * BM * K;
  const size_t Bbase = (size_t)bn * BN * K;

  const int r0 = t >> 2, kc0 = (t & 3) * 8;
  const int r1 = r0 + 64;

  f32x4 acc[4][4] = {};
  const int lm = l & 15;
  const int l4 = l >> 4;
  const int kb8 = l4 * 8;

  const int nk = K / BK;
  for (int kt = 0; kt < nk; ++kt) {
    const size_t gk = (size_t)kt * BK;
    GLD16(Ah + Abase + (size_t)r0 * K + gk + kc0, &sAh[r0 * BK + kc0]);
    GLD16(Ah + Abase + (size_t)r1 * K + gk + kc0, &sAh[r1 * BK + kc0]);
    GLD16(BTh + Bbase + (size_t)r0 * K + gk + kc0, &sBh[r0 * BK + kc0]);
    GLD16(BTh + Bbase + (size_t)r1 * K + gk + kc0, &sBh[r1 * BK + kc0]);
    GLD16(Al + Abase + (size_t)r0 * K + gk + kc0, &sAl[r0 * BK + kc0]);
    GLD16(Al + Abase + (size_t)r1 * K + gk + kc0, &sAl[r1 * BK + kc0]);
    GLD16(BTl + Bbase + (size_t)r0 * K + gk + kc0, &sBl[r0 * BK + kc0]);
    GLD16(BTl + Bbase + (size_t)r1 * K + gk + kc0, &sBl[r1 * BK + kc0]);
    __syncthreads();

    bf16x8 a[4], b[4];
#pragma unroll
    for (int m = 0; m < 4; ++m)
      a[m] = *reinterpret_cast<const bf16x8*>(&sAh[(wr + m * 16 + lm) * BK + kb8]);
#pragma unroll
    for (int n = 0; n < 4; ++n)
      b[n] = *reinterpret_cast<const bf16x8*>(&sBh[(wc + n * 16 + lm) * BK + kb8]);
#pragma unroll
    for (int m = 0; m < 4; ++m)
#pragma unroll
      for (int n = 0; n < 4; ++n)
        acc[m][n] = __builtin_amdgcn_mfma_f32_16x16x32_bf16(a[m], b[n], acc[m][n], 0, 0, 0);

    {
      bf16x8 al_[4], bl_[4];
#pragma unroll
      for (int m = 0; m < 4; ++m)
        al_[m] = *reinterpret_cast<const bf16x8*>(&sAl[(wr + m * 16 + lm) * BK + kb8]);
#pragma unroll
      for (int n = 0; n < 4; ++n)
        bl_[n] = *reinterpret_cast<const bf16x8*>(&sBl[(wc + n * 16 + lm) * BK + kb8]);
#pragma unroll
      for (int m = 0; m < 4; ++m)
#pragma unroll
        for (int n = 0; n < 4; ++n) {
          acc[m][n] = __builtin_amdgcn_mfma_f32_16x16x32_bf16(a[m], bl_[n], acc[m][n], 0, 0, 0);
          acc[m][n] = __builtin_amdgcn_mfma_f32_16x16x32_bf16(al_[m], b[n], acc[m][n], 0, 0, 0);
        }
    }
    __syncthreads();
  }

  const int cr = l4 * 4;
#pragma unroll
  for (int m = 0; m < 4; ++m) {
#pragma unroll
    for (int n = 0; n < 4; ++n) {
      const int c = bn * BN + wc + n * 16 + lm;
#pragma unroll
      for (int j = 0; j < 4; ++j) {
        const int r = bm * BM + wr + m * 16 + cr + j;
        const size_t idx = (size_t)r * N + c;
        const float v = acc[m][n][j];
        Cf[idx] = v;
        Cb[idx] = __float2bfloat16(v);
      }
    }
  }
}

// ---------------- GEMM2/3: 256x256 tile, BK=32, 8 waves, 2-phase + setprio, depth-2 pipeline --
// Same verified sync skeleton as r8's k_gemm_pipe (vmcnt(depth*loads) entry, raw barriers,
// stage kt+2 into pb after post-barrier), scaled to 256^2 for 2x arithmetic intensity.
// EPI 2: Cb=bf16(fast_gelu(v+bias[c]))   (h)
// EPI 3: Cf=v raw partial                 (y split-K, Cf += ks*M*N)
template <int EPI>
__global__ __launch_bounds__(512, 2) void k_gemm_256(const bf16_t* __restrict__ A,
                                                     const bf16_t* __restrict__ BT,
                                                     const float* __restrict__ bias,
                                                     float* __restrict__ Cf,
                                                     bf16_t* __restrict__ Cb,
                                                     int M, int N, int K, int LDK) {
  constexpr int BM = 256, BN = 256, BK = 32;
  __shared__ __align__(16) bf16_t sA[2][BM * BK];  // 2 x 16 KiB
  __shared__ __align__(16) bf16_t sB[2][BN * BK];  // 2 x 16 KiB  (total 64 KiB)

  const int nbn = N / BN;
  const int nwg = gridDim.x;
  const int wg = blockIdx.x;
  const int cpx = nwg >> 3;
  const int swz = (wg & 7) * cpx + (wg >> 3);  // bijective XCD swizzle (nwg % 8 == 0)
  const int bm = swz / nbn, bn = swz % nbn;

  const int ks = blockIdx.y;  // split-K slice
  const size_t k0 = (size_t)ks * K;
  Cf += (size_t)ks * M * N;

  const int t = threadIdx.x;          // 0..511, 8 waves
  const int l = t & 63;
  const int w = t >> 6;
  const int wr = (w >> 2) * 128;      // wave rows: 2 groups of 128
  const int wc = (w & 3) * 64;        // wave cols: 4 groups of 64

  const size_t Abase = (size_t)bm * BM * LDK + k0;
  const size_t Bbase = (size_t)bn * BN * LDK + k0;

  const int lm = l & 15;
  const int l4 = l >> 4;

  // staging: tile 256 rows x 32 cols bf16 = 1024 chunks(16B); c = t + 512p (p=0,1).
  // row r=c>>2, chunk j=c&3; global pre-swizzled j^(r&3); LDS linear at c*16B.
  auto stage = [&](int kt, int pb) {
    const size_t gk = (size_t)kt * BK;
#pragma unroll
    for (int p = 0; p < 2; ++p) {
      const int c = t + 512 * p;
      const int r = c >> 2, j = c & 3;
      const int jg = (j ^ (r & 3)) * 8;
      GLD16(A + Abase + (size_t)r * LDK + gk + jg, &sA[pb][c * 8]);
    }
#pragma unroll
    for (int p = 0; p < 2; ++p) {
      const int c = t + 512 * p;
      const int r = c >> 2, j = c & 3;
      const int jg = (j ^ (r & 3)) * 8;
      GLD16(BT + Bbase + (size_t)r * LDK + gk + jg, &sB[pb][c * 8]);
    }
  };

  f32x4 acc[8][4] = {};
  const int nk = K / BK;

  stage(0, 0);
  stage(1, 1);
  for (int kt = 0; kt < nk; ++kt) {
    const int pb = kt & 1;
    if (kt + 1 < nk) {
      asm volatile("s_waitcnt vmcnt(4)" ::: "memory");   // tile kt landed; kt+1 in flight
    } else {
      asm volatile("s_waitcnt vmcnt(0)" ::: "memory");
    }
    __builtin_amdgcn_s_barrier();                        // publish tile kt to all waves
    __builtin_amdgcn_sched_barrier(0);

    // B fragments (shared by both phases)
    bf16x8 b[4];
#pragma unroll
    for (int n = 0; n < 4; ++n) {
      const int R = wc + n * 16 + lm;
      const int q = l4 ^ (R & 3);
      b[n] = *reinterpret_cast<const bf16x8*>(&sB[pb][R * BK + q * 8]);
    }
    // phase 0: m 0..3
    {
      bf16x8 a[4];
#pragma unroll
      for (int m = 0; m < 4; ++m) {
        const int R = wr + m * 16 + lm;
        const int q = l4 ^ (R & 3);
        a[m] = *reinterpret_cast<const bf16x8*>(&sA[pb][R * BK + q * 8]);
      }
      asm volatile("s_waitcnt lgkmcnt(0)" ::: "memory");
      __builtin_amdgcn_sched_barrier(0);
      __builtin_amdgcn_s_setprio(1);
#pragma unroll
      for (int m = 0; m < 4; ++m)
#pragma unroll
        for (int n = 0; n < 4; ++n)
          acc[m][n] = __builtin_amdgcn_mfma_f32_16x16x32_bf16(a[m], b[n], acc[m][n], 0, 0, 0);
      __builtin_amdgcn_s_setprio(0);
    }
    __builtin_amdgcn_s_barrier();                        // phase boundary (lockstep)
    // phase 1: m 4..7
    {
      bf16x8 a[4];
#pragma unroll
      for (int m = 0; m < 4; ++m) {
        const int R = wr + 64 + m * 16 + lm;
        const int q = l4 ^ (R & 3);
        a[m] = *reinterpret_cast<const bf16x8*>(&sA[pb][R * BK + q * 8]);
      }
      asm volatile("s_waitcnt lgkmcnt(0)" ::: "memory");
      __builtin_amdgcn_sched_barrier(0);
      __builtin_amdgcn_s_setprio(1);
#pragma unroll
      for (int m = 0; m < 4; ++m)
#pragma unroll
        for (int n = 0; n < 4; ++n)
          acc[4 + m][n] = __builtin_amdgcn_mfma_f32_16x16x32_bf16(a[m], b[n], acc[4 + m][n], 0, 0, 0);
      __builtin_amdgcn_s_setprio(0);
    }
    __builtin_amdgcn_sched_barrier(0);
    __builtin_amdgcn_s_barrier();                        // all waves done reading buf pb
    if (kt + 2 < nk) stage(kt + 2, pb);                  // restage same-parity buffer
  }

  // C/D layout (m89-verified): col = lane&15, row = (lane>>4)*4 + j
  const int cr = l4 * 4;
#pragma unroll
  for (int m = 0; m < 8; ++m) {
    const int rbase = bm * BM + wr + ((m < 4) ? m * 16 : 64 + (m - 4) * 16);
#pragma unroll
    for (int n = 0; n < 4; ++n) {
      const int c = bn * BN + wc + n * 16 + lm;
      const float bc = (EPI == 2) ? bias[c] : 0.0f;
#pragma unroll
      for (int j = 0; j < 4; ++j) {
        const int r = rbase + cr + j;
        const size_t idx = (size_t)r * N + c;
        const float v = acc[m][n][j];
        if (EPI == 2) {
          Cb[idx] = __float2bfloat16(fast_gelu(v + bc));
        } else {
          Cf[idx] = v;
        }
      }
    }
  }
}

// ---------------- LN(y0+y1+b2) fused with residual: out = z + tanh(alpha)*ln ----------------
__global__ __launch_bounds__(256) void k_ln_res(const float* __restrict__ y0,
                                                const float* __restrict__ y1,
                                                const float* __restrict__ b2,
                                                const float* __restrict__ z,
                                                const float* __restrict__ gamma,
                                                const float* __restrict__ beta,
                                                const float* __restrict__ alpha,
                                                float* __restrict__ out) {
  const int row = blockIdx.x;
  const int t = threadIdx.x;  // 256 threads * 4 floats = 1024 = D
  const float4 va = reinterpret_cast<const float4*>(y0 + (size_t)row * DD)[t];
  const float4 vb = reinterpret_cast<const float4*>(y1 + (size_t)row * DD)[t];
  const float4 bc = reinterpret_cast<const float4*>(b2)[t];
  float4 v;
  v.x = va.x + vb.x + bc.x; v.y = va.y + vb.y + bc.y;
  v.z = va.z + vb.z + bc.z; v.w = va.w + vb.w + bc.w;
  float s = v.x + v.y + v.z + v.w;
  float q = v.x * v.x + v.y * v.y + v.z * v.z + v.w * v.w;
#pragma unroll
  for (int m = 1; m < 64; m <<= 1) {
    s += __shfl_xor(s, m, 64);
    q += __shfl_xor(q, m, 64);
  }
  __shared__ float ss[4], sq[4];
  if ((t & 63) == 0) { ss[t >> 6] = s; sq[t >> 6] = q; }
  __syncthreads();
  s = ss[0] + ss[1] + ss[2] + ss[3];
  q = sq[0] + sq[1] + sq[2] + sq[3];
  const float mu = s * (1.0f / DD);
  const float var = fmaxf(q * (1.0f / DD) - mu * mu, 0.0f);
  const float rs = rsqrtf(var + 1e-5f);
  const float4 g = reinterpret_cast<const float4*>(gamma)[t];
  const float4 bb = reinterpret_cast<const float4*>(beta)[t];
  const float4 aa = reinterpret_cast<const float4*>(alpha)[t];
  const float4 zz = reinterpret_cast<const float4*>(z + (size_t)row * DD)[t];
  float4 o;
  o.x = zz.x + tanhf(aa.x) * ((v.x - mu) * rs * g.x + bb.x);
  o.y = zz.y + tanhf(aa.y) * ((v.y - mu) * rs * g.y + bb.y);
  o.z = zz.z + tanhf(aa.z) * ((v.z - mu) * rs * g.z + bb.z);
  o.w = zz.w + tanhf(aa.w) * ((v.w - mu) * rs * g.w + bb.w);
  reinterpret_cast<float4*>(out + (size_t)row * DD)[t] = o;
}

extern "C" void kernel_launch(void* const* d_in, const int* in_sizes, int n_in, void* d_out,
                              int out_size, void* d_ws, size_t ws_size, hipStream_t stream) {
  const float* x   = (const float*)d_in[0];
  const float* thQ = (const float*)d_in[1];
  const float* W1  = (const float*)d_in[2];
  const float* b1  = (const float*)d_in[3];
  const float* W2  = (const float*)d_in[4];
  const float* b2  = (const float*)d_in[5];
  const float* gam = (const float*)d_in[6];
  const float* bet = (const float*)d_in[7];
  const float* alp = (const float*)d_in[8];
  float* out = (float*)d_out;

  const int M = in_sizes[0] / DD;  // B*V*T = 8192

  char* ws = (char*)d_ws;
  size_t off = 0;
  auto take = [&](size_t bytes) -> char* {
    char* p = ws + off;
    off += (bytes + 255) & ~(size_t)255;
    return p;
  };
  bf16_t* xh  = (bf16_t*)take((size_t)M * DD * 2);
  bf16_t* xl  = (bf16_t*)take((size_t)M * DD * 2);
  bf16_t* qTh = (bf16_t*)take((size_t)DD * DD * 2);
  bf16_t* qTl = (bf16_t*)take((size_t)DD * DD * 2);
  bf16_t* w1T = (bf16_t*)take((size_t)DD * HH * 2);
  bf16_t* w2T = (bf16_t*)take((size_t)HH * DD * 2);
  float*  zf  = (float*)take((size_t)M * DD * 4);
  bf16_t* zb  = (bf16_t*)take((size_t)M * DD * 2);
  bf16_t* hb  = (bf16_t*)take((size_t)M * HH * 2);
  float*  yf  = (float*)take((size_t)M * DD * 4 * 2);  // 2 split-K partials

  // prep: conversions / transposes
  hipLaunchKernelGGL(k_split_x, dim3(2048), dim3(256), 0, stream, x, xh, xl, M * DD / 4);
  hipLaunchKernelGGL((k_transpose<true>), dim3(DD / 32, DD / 32), dim3(32, 8), 0, stream,
                     thQ, qTh, qTl, DD, DD);
  hipLaunchKernelGGL((k_transpose<false>), dim3(HH / 32, DD / 32), dim3(32, 8), 0, stream,
                     W1, w1T, (bf16_t*)nullptr, DD, HH);
  hipLaunchKernelGGL((k_transpose<false>), dim3(DD / 32, HH / 32), dim3(32, 8), 0, stream,
                     W2, w2T, (bf16_t*)nullptr, HH, DD);

  // z = x @ thetaQ  (split 3-pass, BK=32 proven drain loop)
  hipLaunchKernelGGL(k_gemm_split, dim3((M / 128) * (DD / 128)), dim3(256), 0, stream,
                     xh, xl, qTh, qTl, zf, zb, M, DD, DD);
  // h = gelu(z @ W1 + b1)   (256^2, 2-phase + setprio, counted-vmcnt depth-2)
  hipLaunchKernelGGL((k_gemm_256<2>), dim3((M / 256) * (HH / 256)), dim3(512), 0, stream,
                     zb, w1T, b1, (float*)nullptr, hb, M, HH, DD, DD);
  // y = h @ W2 (split-K=2 raw partials; bias in LN) -> 128 x 2 blocks = 1/CU
  hipLaunchKernelGGL((k_gemm_256<3>), dim3((M / 256) * (DD / 256), 2), dim3(512), 0, stream,
                     hb, w2T, (const float*)nullptr, yf, (bf16_t*)nullptr, M, DD, HH / 2, HH);
  // out = z + tanh(alpha) * LayerNorm(y0+y1+b2)
  hipLaunchKernelGGL(k_ln_res, dim3(M), dim3(256), 0, stream,
                     yf, yf + (size_t)M * DD, b2, zf, gam, bet, alp, out);
}

// Round 10
// 353.590 us; speedup vs baseline: 1.1842x; 1.0203x over previous
//
#include <hip/hip_runtime.h>
#include <hip/hip_bf16.h>
#include <cstdint>
#include <math.h>

typedef __hip_bfloat16 bf16_t;
typedef __attribute__((ext_vector_type(8))) __bf16 bf16x8;
typedef __attribute__((ext_vector_type(4))) float f32x4;

static_assert(sizeof(bf16x8) == 16, "bf16x8 must be 4 VGPRs");

static constexpr int DD = 1024;   // D
static constexpr int HH = 4096;   // H = 4*D

// async global->LDS, 16B per lane.
#define GLD16(gp, lp)                                                                              \
  __builtin_amdgcn_global_load_lds(                                                                \
      (__attribute__((address_space(1))) void*)(uintptr_t)(gp),                                    \
      (__attribute__((address_space(3))) void*)(uint32_t)(uintptr_t)(lp), 16, 0, 0)

#if !__has_builtin(__builtin_amdgcn_exp2f)
#define __builtin_amdgcn_exp2f(x) exp2f(x)
#endif
#if !__has_builtin(__builtin_amdgcn_rcpf)
#define __builtin_amdgcn_rcpf(x) (1.0f / (x))
#endif

// Logistic GELU approx (|err|<=~0.02 on h; reaches output via LN * tanh(0.01) -> ~1e-4).
__device__ __forceinline__ float fast_gelu(float u) {
  const float t = __builtin_amdgcn_exp2f(-2.4554089f * u);
  return u * __builtin_amdgcn_rcpf(1.0f + t);
}

// ---------------- fp32 -> bf16 hi/lo split (for x) ----------------
__global__ __launch_bounds__(256) void k_split_x(const float* __restrict__ x,
                                                 bf16_t* __restrict__ xh,
                                                 bf16_t* __restrict__ xl, int n4) {
  int i = blockIdx.x * 256 + threadIdx.x;
  const int stride = gridDim.x * 256;
  for (; i < n4; i += stride) {
    const float4 v = reinterpret_cast<const float4*>(x)[i];
    float vv[4] = {v.x, v.y, v.z, v.w};
    union { bf16_t b[4]; short4 s; } H, L;
#pragma unroll
    for (int j = 0; j < 4; ++j) {
      H.b[j] = __float2bfloat16(vv[j]);
      L.b[j] = __float2bfloat16(vv[j] - __bfloat162float(H.b[j]));
    }
    reinterpret_cast<short4*>(xh)[i] = H.s;
    reinterpret_cast<short4*>(xl)[i] = L.s;
  }
}

// ---------------- transpose + convert weights: W[K][N] f32 -> WT[N][K] bf16 (optional lo) -----
template <bool SPLIT>
__global__ __launch_bounds__(256) void k_transpose(const float* __restrict__ W,
                                                   bf16_t* __restrict__ Th,
                                                   bf16_t* __restrict__ Tl, int K, int N) {
  __shared__ float tile[32][33];
  const int n0 = blockIdx.x * 32, k0 = blockIdx.y * 32;
  const int tx = threadIdx.x, ty = threadIdx.y;  // block (32,8)
#pragma unroll
  for (int r = 0; r < 4; ++r) {
    const int k = ty + r * 8;
    tile[k][tx] = W[(size_t)(k0 + k) * N + n0 + tx];
  }
  __syncthreads();
#pragma unroll
  for (int r = 0; r < 4; ++r) {
    const int n = ty + r * 8;
    const float v = tile[tx][n];
    const bf16_t h = __float2bfloat16(v);
    Th[(size_t)(n0 + n) * K + k0 + tx] = h;
    if (SPLIT) Tl[(size_t)(n0 + n) * K + k0 + tx] = __float2bfloat16(v - __bfloat162float(h));
  }
}

// ---------------- GEMM1 (SPLIT 3-pass, BK=32, counted-vmcnt depth-2 pipeline) ---------------
// r8-verified sync skeleton (vmcnt(loads*depth) entry, raw barriers, restage kt+2) ported to
// the 4-array split staging. LDS 2dbuf x 4 x 8KB = 64 KiB.
__global__ __launch_bounds__(256) void k_gemm_split(const bf16_t* __restrict__ Ah,
                                                    const bf16_t* __restrict__ Al,
                                                    const bf16_t* __restrict__ BTh,
                                                    const bf16_t* __restrict__ BTl,
                                                    float* __restrict__ Cf,
                                                    bf16_t* __restrict__ Cb,
                                                    int M, int N, int K) {
  constexpr int BM = 128, BN = 128, BK = 32;
  __shared__ __align__(16) bf16_t sAh[2][BM * BK];
  __shared__ __align__(16) bf16_t sBh[2][BN * BK];
  __shared__ __align__(16) bf16_t sAl[2][BM * BK];
  __shared__ __align__(16) bf16_t sBl[2][BN * BK];

  const int nbn = N / BN;
  const int nwg = gridDim.x;
  const int wg = blockIdx.x;
  const int cpx = nwg >> 3;
  const int swz = (wg & 7) * cpx + (wg >> 3);
  const int bm = swz / nbn, bn = swz % nbn;

  const int t = threadIdx.x;
  const int l = t & 63;
  const int w = t >> 6;
  const int wr = (w >> 1) * 64, wc = (w & 1) * 64;

  const size_t Abase = (size_t)bm * BM * K;
  const size_t Bbase = (size_t)bn * BN * K;

  const int r0 = t >> 2, kc0 = (t & 3) * 8;
  const int r1 = r0 + 64;

  f32x4 acc[4][4] = {};
  const int lm = l & 15;
  const int l4 = l >> 4;
  const int kb8 = l4 * 8;

  auto stage = [&](int kt, int pb) {
    const size_t gk = (size_t)kt * BK;
    GLD16(Ah + Abase + (size_t)r0 * K + gk + kc0, &sAh[pb][r0 * BK + kc0]);
    GLD16(Ah + Abase + (size_t)r1 * K + gk + kc0, &sAh[pb][r1 * BK + kc0]);
    GLD16(BTh + Bbase + (size_t)r0 * K + gk + kc0, &sBh[pb][r0 * BK + kc0]);
    GLD16(BTh + Bbase + (size_t)r1 * K + gk + kc0, &sBh[pb][r1 * BK + kc0]);
    GLD16(Al + Abase + (size_t)r0 * K + gk + kc0, &sAl[pb][r0 * BK + kc0]);
    GLD16(Al + Abase + (size_t)r1 * K + gk + kc0, &sAl[pb][r1 * BK + kc0]);
    GLD16(BTl + Bbase + (size_t)r0 * K + gk + kc0, &sBl[pb][r0 * BK + kc0]);
    GLD16(BTl + Bbase + (size_t)r1 * K + gk + kc0, &sBl[pb][r1 * BK + kc0]);
  };

  const int nk = K / BK;
  stage(0, 0);
  stage(1, 1);
  for (int kt = 0; kt < nk; ++kt) {
    const int pb = kt & 1;
    if (kt + 1 < nk) {
      asm volatile("s_waitcnt vmcnt(8)" ::: "memory");
    } else {
      asm volatile("s_waitcnt vmcnt(0)" ::: "memory");
    }
    __builtin_amdgcn_s_barrier();
    __builtin_amdgcn_sched_barrier(0);

    bf16x8 a[4], b[4];
#pragma unroll
    for (int m = 0; m < 4; ++m)
      a[m] = *reinterpret_cast<const bf16x8*>(&sAh[pb][(wr + m * 16 + lm) * BK + kb8]);
#pragma unroll
    for (int n = 0; n < 4; ++n)
      b[n] = *reinterpret_cast<const bf16x8*>(&sBh[pb][(wc + n * 16 + lm) * BK + kb8]);
#pragma unroll
    for (int m = 0; m < 4; ++m)
#pragma unroll
      for (int n = 0; n < 4; ++n)
        acc[m][n] = __builtin_amdgcn_mfma_f32_16x16x32_bf16(a[m], b[n], acc[m][n], 0, 0, 0);

    {
      bf16x8 al_[4], bl_[4];
#pragma unroll
      for (int m = 0; m < 4; ++m)
        al_[m] = *reinterpret_cast<const bf16x8*>(&sAl[pb][(wr + m * 16 + lm) * BK + kb8]);
#pragma unroll
      for (int n = 0; n < 4; ++n)
        bl_[n] = *reinterpret_cast<const bf16x8*>(&sBl[pb][(wc + n * 16 + lm) * BK + kb8]);
#pragma unroll
      for (int m = 0; m < 4; ++m)
#pragma unroll
        for (int n = 0; n < 4; ++n) {
          acc[m][n] = __builtin_amdgcn_mfma_f32_16x16x32_bf16(a[m], bl_[n], acc[m][n], 0, 0, 0);
          acc[m][n] = __builtin_amdgcn_mfma_f32_16x16x32_bf16(al_[m], b[n], acc[m][n], 0, 0, 0);
        }
    }

    __builtin_amdgcn_sched_barrier(0);
    __builtin_amdgcn_s_barrier();
    if (kt + 2 < nk) stage(kt + 2, pb);
  }

  const int cr = l4 * 4;
#pragma unroll
  for (int m = 0; m < 4; ++m) {
#pragma unroll
    for (int n = 0; n < 4; ++n) {
      const int c = bn * BN + wc + n * 16 + lm;
#pragma unroll
      for (int j = 0; j < 4; ++j) {
        const int r = bm * BM + wr + m * 16 + cr + j;
        const size_t idx = (size_t)r * N + c;
        const float v = acc[m][n][j];
        Cf[idx] = v;
        Cb[idx] = __float2bfloat16(v);
      }
    }
  }
}

// ---------------- GEMM2/3: 256x256, BK=32, 8 waves, depth-2 counted vmcnt --------------------
// r9 changes: (a) swizzle uses (r>>2)&3 (kills the 4-way read conflict -> 2-way free);
// (b) mid-phase barrier + forced lgkmcnt(0) pins removed -> compiler interleaves ds_read/MFMA.
// EPI 2: Cb=bf16(fast_gelu(v+bias[c]))   (h)
// EPI 3: Cf=v raw partial                 (y split-K, Cf += ks*M*N)
template <int EPI>
__global__ __launch_bounds__(512, 2) void k_gemm_256(const bf16_t* __restrict__ A,
                                                     const bf16_t* __restrict__ BT,
                                                     const float* __restrict__ bias,
                                                     float* __restrict__ Cf,
                                                     bf16_t* __restrict__ Cb,
                                                     int M, int N, int K, int LDK) {
  constexpr int BM = 256, BN = 256, BK = 32;
  __shared__ __align__(16) bf16_t sA[2][BM * BK];  // 2 x 16 KiB
  __shared__ __align__(16) bf16_t sB[2][BN * BK];  // 2 x 16 KiB  (total 64 KiB)

  const int nbn = N / BN;
  const int nwg = gridDim.x;
  const int wg = blockIdx.x;
  const int cpx = nwg >> 3;
  const int swz = (wg & 7) * cpx + (wg >> 3);  // bijective XCD swizzle (nwg % 8 == 0)
  const int bm = swz / nbn, bn = swz % nbn;

  const int ks = blockIdx.y;  // split-K slice
  const size_t k0 = (size_t)ks * K;
  Cf += (size_t)ks * M * N;

  const int t = threadIdx.x;          // 0..511, 8 waves
  const int l = t & 63;
  const int w = t >> 6;
  const int wr = (w >> 2) * 128;      // wave rows: 2 groups of 128
  const int wc = (w & 3) * 64;        // wave cols: 4 groups of 64

  const size_t Abase = (size_t)bm * BM * LDK + k0;
  const size_t Bbase = (size_t)bn * BN * LDK + k0;

  const int lm = l & 15;
  const int l4 = l >> 4;

  // staging: c = t + 512p; row r=c>>2, slot j=c&3; global chunk jg = j ^ ((r>>2)&3).
  // Read side: slot q = l4 ^ ((R>>2)&3). Bank pair (R&1, q) -> 8 combos x 2 lanes = 2-way free.
  auto stage = [&](int kt, int pb) {
    const size_t gk = (size_t)kt * BK;
#pragma unroll
    for (int p = 0; p < 2; ++p) {
      const int c = t + 512 * p;
      const int r = c >> 2, j = c & 3;
      const int jg = (j ^ ((r >> 2) & 3)) * 8;
      GLD16(A + Abase + (size_t)r * LDK + gk + jg, &sA[pb][c * 8]);
    }
#pragma unroll
    for (int p = 0; p < 2; ++p) {
      const int c = t + 512 * p;
      const int r = c >> 2, j = c & 3;
      const int jg = (j ^ ((r >> 2) & 3)) * 8;
      GLD16(BT + Bbase + (size_t)r * LDK + gk + jg, &sB[pb][c * 8]);
    }
  };

  f32x4 acc[8][4] = {};
  const int nk = K / BK;

  stage(0, 0);
  stage(1, 1);
  for (int kt = 0; kt < nk; ++kt) {
    const int pb = kt & 1;
    if (kt + 1 < nk) {
      asm volatile("s_waitcnt vmcnt(4)" ::: "memory");   // tile kt landed; kt+1 in flight
    } else {
      asm volatile("s_waitcnt vmcnt(0)" ::: "memory");
    }
    __builtin_amdgcn_s_barrier();                        // publish tile kt to all waves
    __builtin_amdgcn_sched_barrier(0);

    bf16x8 b[4];
#pragma unroll
    for (int n = 0; n < 4; ++n) {
      const int R = wc + n * 16 + lm;
      const int q = l4 ^ ((R >> 2) & 3);
      b[n] = *reinterpret_cast<const bf16x8*>(&sB[pb][R * BK + q * 8]);
    }
    __builtin_amdgcn_s_setprio(1);
    {
      bf16x8 a[4];
#pragma unroll
      for (int m = 0; m < 4; ++m) {
        const int R = wr + m * 16 + lm;
        const int q = l4 ^ ((R >> 2) & 3);
        a[m] = *reinterpret_cast<const bf16x8*>(&sA[pb][R * BK + q * 8]);
      }
#pragma unroll
      for (int m = 0; m < 4; ++m)
#pragma unroll
        for (int n = 0; n < 4; ++n)
          acc[m][n] = __builtin_amdgcn_mfma_f32_16x16x32_bf16(a[m], b[n], acc[m][n], 0, 0, 0);
    }
    {
      bf16x8 a[4];
#pragma unroll
      for (int m = 0; m < 4; ++m) {
        const int R = wr + 64 + m * 16 + lm;
        const int q = l4 ^ ((R >> 2) & 3);
        a[m] = *reinterpret_cast<const bf16x8*>(&sA[pb][R * BK + q * 8]);
      }
#pragma unroll
      for (int m = 0; m < 4; ++m)
#pragma unroll
        for (int n = 0; n < 4; ++n)
          acc[4 + m][n] = __builtin_amdgcn_mfma_f32_16x16x32_bf16(a[m], b[n], acc[4 + m][n], 0, 0, 0);
    }
    __builtin_amdgcn_s_setprio(0);

    __builtin_amdgcn_sched_barrier(0);
    __builtin_amdgcn_s_barrier();                        // all waves done reading buf pb
    if (kt + 2 < nk) stage(kt + 2, pb);                  // restage same-parity buffer
  }

  // C/D layout (m89-verified): col = lane&15, row = (lane>>4)*4 + j
  const int cr = l4 * 4;
#pragma unroll
  for (int m = 0; m < 8; ++m) {
    const int rbase = bm * BM + wr + ((m < 4) ? m * 16 : 64 + (m - 4) * 16);
#pragma unroll
    for (int n = 0; n < 4; ++n) {
      const int c = bn * BN + wc + n * 16 + lm;
      const float bc = (EPI == 2) ? bias[c] : 0.0f;
#pragma unroll
      for (int j = 0; j < 4; ++j) {
        const int r = rbase + cr + j;
        const size_t idx = (size_t)r * N + c;
        const float v = acc[m][n][j];
        if (EPI == 2) {
          Cb[idx] = __float2bfloat16(fast_gelu(v + bc));
        } else {
          Cf[idx] = v;
        }
      }
    }
  }
}

// ---------------- LN(y0+y1+b2) fused with residual: out = z + tanh(alpha)*ln ----------------
__global__ __launch_bounds__(256) void k_ln_res(const float* __restrict__ y0,
                                                const float* __restrict__ y1,
                                                const float* __restrict__ b2,
                                                const float* __restrict__ z,
                                                const float* __restrict__ gamma,
                                                const float* __restrict__ beta,
                                                const float* __restrict__ alpha,
                                                float* __restrict__ out) {
  const int row = blockIdx.x;
  const int t = threadIdx.x;  // 256 threads * 4 floats = 1024 = D
  const float4 va = reinterpret_cast<const float4*>(y0 + (size_t)row * DD)[t];
  const float4 vb = reinterpret_cast<const float4*>(y1 + (size_t)row * DD)[t];
  const float4 bc = reinterpret_cast<const float4*>(b2)[t];
  float4 v;
  v.x = va.x + vb.x + bc.x; v.y = va.y + vb.y + bc.y;
  v.z = va.z + vb.z + bc.z; v.w = va.w + vb.w + bc.w;
  float s = v.x + v.y + v.z + v.w;
  float q = v.x * v.x + v.y * v.y + v.z * v.z + v.w * v.w;
#pragma unroll
  for (int m = 1; m < 64; m <<= 1) {
    s += __shfl_xor(s, m, 64);
    q += __shfl_xor(q, m, 64);
  }
  __shared__ float ss[4], sq[4];
  if ((t & 63) == 0) { ss[t >> 6] = s; sq[t >> 6] = q; }
  __syncthreads();
  s = ss[0] + ss[1] + ss[2] + ss[3];
  q = sq[0] + sq[1] + sq[2] + sq[3];
  const float mu = s * (1.0f / DD);
  const float var = fmaxf(q * (1.0f / DD) - mu * mu, 0.0f);
  const float rs = rsqrtf(var + 1e-5f);
  const float4 g = reinterpret_cast<const float4*>(gamma)[t];
  const float4 bb = reinterpret_cast<const float4*>(beta)[t];
  const float4 aa = reinterpret_cast<const float4*>(alpha)[t];
  const float4 zz = reinterpret_cast<const float4*>(z + (size_t)row * DD)[t];
  float4 o;
  o.x = zz.x + tanhf(aa.x) * ((v.x - mu) * rs * g.x + bb.x);
  o.y = zz.y + tanhf(aa.y) * ((v.y - mu) * rs * g.y + bb.y);
  o.z = zz.z + tanhf(aa.z) * ((v.z - mu) * rs * g.z + bb.z);
  o.w = zz.w + tanhf(aa.w) * ((v.w - mu) * rs * g.w + bb.w);
  reinterpret_cast<float4*>(out + (size_t)row * DD)[t] = o;
}

extern "C" void kernel_launch(void* const* d_in, const int* in_sizes, int n_in, void* d_out,
                              int out_size, void* d_ws, size_t ws_size, hipStream_t stream) {
  const float* x   = (const float*)d_in[0];
  const float* thQ = (const float*)d_in[1];
  const float* W1  = (const float*)d_in[2];
  const float* b1  = (const float*)d_in[3];
  const float* W2  = (const float*)d_in[4];
  const float* b2  = (const float*)d_in[5];
  const float* gam = (const float*)d_in[6];
  const float* bet = (const float*)d_in[7];
  const float* alp = (const float*)d_in[8];
  float* out = (float*)d_out;

  const int M = in_sizes[0] / DD;  // B*V*T = 8192

  char* ws = (char*)d_ws;
  size_t off = 0;
  auto take = [&](size_t bytes) -> char* {
    char* p = ws + off;
    off += (bytes + 255) & ~(size_t)255;
    return p;
  };
  bf16_t* xh  = (bf16_t*)take((size_t)M * DD * 2);
  bf16_t* xl  = (bf16_t*)take((size_t)M * DD * 2);
  bf16_t* qTh = (bf16_t*)take((size_t)DD * DD * 2);
  bf16_t* qTl = (bf16_t*)take((size_t)DD * DD * 2);
  bf16_t* w1T = (bf16_t*)take((size_t)DD * HH * 2);
  bf16_t* w2T = (bf16_t*)take((size_t)HH * DD * 2);
  float*  zf  = (float*)take((size_t)M * DD * 4);
  bf16_t* zb  = (bf16_t*)take((size_t)M * DD * 2);
  bf16_t* hb  = (bf16_t*)take((size_t)M * HH * 2);
  float*  yf  = (float*)take((size_t)M * DD * 4 * 2);  // 2 split-K partials

  // prep: conversions / transposes
  hipLaunchKernelGGL(k_split_x, dim3(2048), dim3(256), 0, stream, x, xh, xl, M * DD / 4);
  hipLaunchKernelGGL((k_transpose<true>), dim3(DD / 32, DD / 32), dim3(32, 8), 0, stream,
                     thQ, qTh, qTl, DD, DD);
  hipLaunchKernelGGL((k_transpose<false>), dim3(HH / 32, DD / 32), dim3(32, 8), 0, stream,
                     W1, w1T, (bf16_t*)nullptr, DD, HH);
  hipLaunchKernelGGL((k_transpose<false>), dim3(DD / 32, HH / 32), dim3(32, 8), 0, stream,
                     W2, w2T, (bf16_t*)nullptr, HH, DD);

  // z = x @ thetaQ  (split 3-pass, BK=32, counted-vmcnt depth-2 pipeline)
  hipLaunchKernelGGL(k_gemm_split, dim3((M / 128) * (DD / 128)), dim3(256), 0, stream,
                     xh, xl, qTh, qTl, zf, zb, M, DD, DD);
  // h = gelu(z @ W1 + b1)   (256^2, conflict-free swizzle, compiler-interleaved)
  hipLaunchKernelGGL((k_gemm_256<2>), dim3((M / 256) * (HH / 256)), dim3(512), 0, stream,
                     zb, w1T, b1, (float*)nullptr, hb, M, HH, DD, DD);
  // y = h @ W2 (split-K=2 raw partials; bias in LN)
  hipLaunchKernelGGL((k_gemm_256<3>), dim3((M / 256) * (DD / 256), 2), dim3(512), 0, stream,
                     hb, w2T, (const float*)nullptr, yf, (bf16_t*)nullptr, M, DD, HH / 2, HH);
  // out = z + tanh(alpha) * LayerNorm(y0+y1+b2)
  hipLaunchKernelGGL(k_ln_res, dim3(M), dim3(256), 0, stream,
                     yf, yf + (size_t)M * DD, b2, zf, gam, bet, alp, out);
}

// Round 11
// 341.899 us; speedup vs baseline: 1.2247x; 1.0342x over previous
//
#include <hip/hip_runtime.h>
#include <hip/hip_bf16.h>
#include <cstdint>
#include <math.h>

typedef __hip_bfloat16 bf16_t;
typedef __attribute__((ext_vector_type(8))) __bf16 bf16x8;
typedef __attribute__((ext_vector_type(4))) float f32x4;

static_assert(sizeof(bf16x8) == 16, "bf16x8 must be 4 VGPRs");

static constexpr int DD = 1024;   // D
static constexpr int HH = 4096;   // H = 4*D

// async global->LDS, 16B per lane.
#define GLD16(gp, lp)                                                                              \
  __builtin_amdgcn_global_load_lds(                                                                \
      (__attribute__((address_space(1))) void*)(uintptr_t)(gp),                                    \
      (__attribute__((address_space(3))) void*)(uint32_t)(uintptr_t)(lp), 16, 0, 0)

#if !__has_builtin(__builtin_amdgcn_exp2f)
#define __builtin_amdgcn_exp2f(x) exp2f(x)
#endif
#if !__has_builtin(__builtin_amdgcn_rcpf)
#define __builtin_amdgcn_rcpf(x) (1.0f / (x))
#endif

// Logistic GELU approx (|err|<=~0.02 on h; reaches output via LN * tanh(0.01) -> ~1e-4).
__device__ __forceinline__ float fast_gelu(float u) {
  const float t = __builtin_amdgcn_exp2f(-2.4554089f * u);
  return u * __builtin_amdgcn_rcpf(1.0f + t);
}

// ---------------- fp32 -> bf16 hi/lo split (for x) ----------------
__global__ __launch_bounds__(256) void k_split_x(const float* __restrict__ x,
                                                 bf16_t* __restrict__ xh,
                                                 bf16_t* __restrict__ xl, int n4) {
  int i = blockIdx.x * 256 + threadIdx.x;
  const int stride = gridDim.x * 256;
  for (; i < n4; i += stride) {
    const float4 v = reinterpret_cast<const float4*>(x)[i];
    float vv[4] = {v.x, v.y, v.z, v.w};
    union { bf16_t b[4]; short4 s; } H, L;
#pragma unroll
    for (int j = 0; j < 4; ++j) {
      H.b[j] = __float2bfloat16(vv[j]);
      L.b[j] = __float2bfloat16(vv[j] - __bfloat162float(H.b[j]));
    }
    reinterpret_cast<short4*>(xh)[i] = H.s;
    reinterpret_cast<short4*>(xl)[i] = L.s;
  }
}

// ---------------- transpose + convert weights: W[K][N] f32 -> WT[N][K] bf16 (optional lo) -----
template <bool SPLIT>
__global__ __launch_bounds__(256) void k_transpose(const float* __restrict__ W,
                                                   bf16_t* __restrict__ Th,
                                                   bf16_t* __restrict__ Tl, int K, int N) {
  __shared__ float tile[32][33];
  const int n0 = blockIdx.x * 32, k0 = blockIdx.y * 32;
  const int tx = threadIdx.x, ty = threadIdx.y;  // block (32,8)
#pragma unroll
  for (int r = 0; r < 4; ++r) {
    const int k = ty + r * 8;
    tile[k][tx] = W[(size_t)(k0 + k) * N + n0 + tx];
  }
  __syncthreads();
#pragma unroll
  for (int r = 0; r < 4; ++r) {
    const int n = ty + r * 8;
    const float v = tile[tx][n];
    const bf16_t h = __float2bfloat16(v);
    Th[(size_t)(n0 + n) * K + k0 + tx] = h;
    if (SPLIT) Tl[(size_t)(n0 + n) * K + k0 + tx] = __float2bfloat16(v - __bfloat162float(h));
  }
}

// ---------------- GEMM1 (SPLIT 3-pass, BK=32, counted-vmcnt depth-2 pipeline) ---------------
__global__ __launch_bounds__(256) void k_gemm_split(const bf16_t* __restrict__ Ah,
                                                    const bf16_t* __restrict__ Al,
                                                    const bf16_t* __restrict__ BTh,
                                                    const bf16_t* __restrict__ BTl,
                                                    float* __restrict__ Cf,
                                                    bf16_t* __restrict__ Cb,
                                                    int M, int N, int K) {
  constexpr int BM = 128, BN = 128, BK = 32;
  __shared__ __align__(16) bf16_t sAh[2][BM * BK];
  __shared__ __align__(16) bf16_t sBh[2][BN * BK];
  __shared__ __align__(16) bf16_t sAl[2][BM * BK];
  __shared__ __align__(16) bf16_t sBl[2][BN * BK];

  const int nbn = N / BN;
  const int nwg = gridDim.x;
  const int wg = blockIdx.x;
  const int cpx = nwg >> 3;
  const int swz = (wg & 7) * cpx + (wg >> 3);
  const int bm = swz / nbn, bn = swz % nbn;

  const int t = threadIdx.x;
  const int l = t & 63;
  const int w = t >> 6;
  const int wr = (w >> 1) * 64, wc = (w & 1) * 64;

  const size_t Abase = (size_t)bm * BM * K;
  const size_t Bbase = (size_t)bn * BN * K;

  const int r0 = t >> 2, kc0 = (t & 3) * 8;
  const int r1 = r0 + 64;

  f32x4 acc[4][4] = {};
  const int lm = l & 15;
  const int l4 = l >> 4;
  const int kb8 = l4 * 8;

  auto stage = [&](int kt, int pb) {
    const size_t gk = (size_t)kt * BK;
    GLD16(Ah + Abase + (size_t)r0 * K + gk + kc0, &sAh[pb][r0 * BK + kc0]);
    GLD16(Ah + Abase + (size_t)r1 * K + gk + kc0, &sAh[pb][r1 * BK + kc0]);
    GLD16(BTh + Bbase + (size_t)r0 * K + gk + kc0, &sBh[pb][r0 * BK + kc0]);
    GLD16(BTh + Bbase + (size_t)r1 * K + gk + kc0, &sBh[pb][r1 * BK + kc0]);
    GLD16(Al + Abase + (size_t)r0 * K + gk + kc0, &sAl[pb][r0 * BK + kc0]);
    GLD16(Al + Abase + (size_t)r1 * K + gk + kc0, &sAl[pb][r1 * BK + kc0]);
    GLD16(BTl + Bbase + (size_t)r0 * K + gk + kc0, &sBl[pb][r0 * BK + kc0]);
    GLD16(BTl + Bbase + (size_t)r1 * K + gk + kc0, &sBl[pb][r1 * BK + kc0]);
  };

  const int nk = K / BK;
  stage(0, 0);
  stage(1, 1);
  for (int kt = 0; kt < nk; ++kt) {
    const int pb = kt & 1;
    if (kt + 1 < nk) {
      asm volatile("s_waitcnt vmcnt(8)" ::: "memory");
    } else {
      asm volatile("s_waitcnt vmcnt(0)" ::: "memory");
    }
    __builtin_amdgcn_s_barrier();
    __builtin_amdgcn_sched_barrier(0);

    bf16x8 a[4], b[4];
#pragma unroll
    for (int m = 0; m < 4; ++m)
      a[m] = *reinterpret_cast<const bf16x8*>(&sAh[pb][(wr + m * 16 + lm) * BK + kb8]);
#pragma unroll
    for (int n = 0; n < 4; ++n)
      b[n] = *reinterpret_cast<const bf16x8*>(&sBh[pb][(wc + n * 16 + lm) * BK + kb8]);
#pragma unroll
    for (int m = 0; m < 4; ++m)
#pragma unroll
      for (int n = 0; n < 4; ++n)
        acc[m][n] = __builtin_amdgcn_mfma_f32_16x16x32_bf16(a[m], b[n], acc[m][n], 0, 0, 0);

    {
      bf16x8 al_[4], bl_[4];
#pragma unroll
      for (int m = 0; m < 4; ++m)
        al_[m] = *reinterpret_cast<const bf16x8*>(&sAl[pb][(wr + m * 16 + lm) * BK + kb8]);
#pragma unroll
      for (int n = 0; n < 4; ++n)
        bl_[n] = *reinterpret_cast<const bf16x8*>(&sBl[pb][(wc + n * 16 + lm) * BK + kb8]);
#pragma unroll
      for (int m = 0; m < 4; ++m)
#pragma unroll
        for (int n = 0; n < 4; ++n) {
          acc[m][n] = __builtin_amdgcn_mfma_f32_16x16x32_bf16(a[m], bl_[n], acc[m][n], 0, 0, 0);
          acc[m][n] = __builtin_amdgcn_mfma_f32_16x16x32_bf16(al_[m], b[n], acc[m][n], 0, 0, 0);
        }
    }

    __builtin_amdgcn_sched_barrier(0);
    __builtin_amdgcn_s_barrier();
    if (kt + 2 < nk) stage(kt + 2, pb);
  }

  const int cr = l4 * 4;
#pragma unroll
  for (int m = 0; m < 4; ++m) {
#pragma unroll
    for (int n = 0; n < 4; ++n) {
      const int c = bn * BN + wc + n * 16 + lm;
#pragma unroll
      for (int j = 0; j < 4; ++j) {
        const int r = bm * BM + wr + m * 16 + cr + j;
        const size_t idx = (size_t)r * N + c;
        const float v = acc[m][n][j];
        Cf[idx] = v;
        Cb[idx] = __float2bfloat16(v);
      }
    }
  }
}

// ---------------- GEMM2/3: 256x256, BK=64 (128B rows, r8's PROVEN 0-conflict swizzle) --------
// 128 KiB dynamic LDS (2dbuf x 32KiB x {A,B}); counted-vmcnt depth-2 skeleton (r8-verified).
// r10 lesson: BK=32's 64B-row geometry carries a fixed 6.29M-conflict cost no XOR fixes;
// BK=64's j^(r&7) measured exactly 0 on this HW.
// EPI 2: Cb=bf16(fast_gelu(v+bias[c]))   (h)
// EPI 3: Cf=v raw partial                 (y split-K, Cf += ks*M*N)
template <int EPI>
__global__ __launch_bounds__(512, 2) void k_gemm_256(const bf16_t* __restrict__ A,
                                                     const bf16_t* __restrict__ BT,
                                                     const float* __restrict__ bias,
                                                     float* __restrict__ Cf,
                                                     bf16_t* __restrict__ Cb,
                                                     int M, int N, int K, int LDK) {
  constexpr int BM = 256, BN = 256, BK = 64;
  extern __shared__ __align__(16) bf16_t smem[];
  bf16_t* sA0 = smem;                    // [256*64] = 32 KiB
  bf16_t* sA1 = smem + BM * BK;
  bf16_t* sB0 = smem + 2 * BM * BK;
  bf16_t* sB1 = smem + 3 * BM * BK;      // total 128 KiB

  const int nbn = N / BN;
  const int nwg = gridDim.x;
  const int wg = blockIdx.x;
  const int cpx = nwg >> 3;
  const int swz = (wg & 7) * cpx + (wg >> 3);  // bijective XCD swizzle (nwg % 8 == 0)
  const int bm = swz / nbn, bn = swz % nbn;

  const int ks = blockIdx.y;  // split-K slice
  const size_t k0 = (size_t)ks * K;
  Cf += (size_t)ks * M * N;

  const int t = threadIdx.x;          // 0..511, 8 waves
  const int l = t & 63;
  const int w = t >> 6;
  const int wr = (w >> 2) * 128;      // wave rows: 2 groups of 128
  const int wc = (w & 3) * 64;        // wave cols: 4 groups of 64

  const size_t Abase = (size_t)bm * BM * LDK + k0;
  const size_t Bbase = (size_t)bn * BN * LDK + k0;

  const int lm = l & 15;
  const int l4 = l >> 4;

  // staging: 2048 chunks/array; c = t + 512p (p=0..3); row r=c>>3, slot j=c&7;
  // global chunk jg = j ^ (r&7); LDS linear at c*16B. (r8-verified: 0 conflicts)
  auto stage = [&](int kt, bf16_t* dA, bf16_t* dB) {
    const size_t gk = (size_t)kt * BK;
#pragma unroll
    for (int p = 0; p < 4; ++p) {
      const int c = t + 512 * p;
      const int r = c >> 3, j = c & 7;
      const int jg = (j ^ (r & 7)) * 8;
      GLD16(A + Abase + (size_t)r * LDK + gk + jg, dA + c * 8);
    }
#pragma unroll
    for (int p = 0; p < 4; ++p) {
      const int c = t + 512 * p;
      const int r = c >> 3, j = c & 7;
      const int jg = (j ^ (r & 7)) * 8;
      GLD16(BT + Bbase + (size_t)r * LDK + gk + jg, dB + c * 8);
    }
  };

  f32x4 acc[8][4] = {};
  const int nk = K / BK;

  stage(0, sA0, sB0);
  stage(1, sA1, sB1);
  for (int kt = 0; kt < nk; ++kt) {
    const int pb = kt & 1;
    bf16_t* cA = pb ? sA1 : sA0;
    bf16_t* cB = pb ? sB1 : sB0;
    if (kt + 1 < nk) {
      asm volatile("s_waitcnt vmcnt(8)" ::: "memory");   // tile kt landed; kt+1 in flight
    } else {
      asm volatile("s_waitcnt vmcnt(0)" ::: "memory");
    }
    __builtin_amdgcn_s_barrier();                        // publish tile kt to all waves
    __builtin_amdgcn_sched_barrier(0);

    __builtin_amdgcn_s_setprio(1);
#pragma unroll
    for (int h = 0; h < 2; ++h) {                        // two K=32 subtiles
      bf16x8 b[4];
#pragma unroll
      for (int n = 0; n < 4; ++n) {
        const int R = wc + n * 16 + lm;
        const int q = (l4 + 4 * h) ^ (R & 7);
        b[n] = *reinterpret_cast<const bf16x8*>(&cB[R * BK + q * 8]);
      }
      bf16x8 a[8];
#pragma unroll
      for (int m = 0; m < 8; ++m) {
        const int R = wr + m * 16 + lm;
        const int q = (l4 + 4 * h) ^ (R & 7);
        a[m] = *reinterpret_cast<const bf16x8*>(&cA[R * BK + q * 8]);
      }
#pragma unroll
      for (int m = 0; m < 8; ++m)
#pragma unroll
        for (int n = 0; n < 4; ++n)
          acc[m][n] = __builtin_amdgcn_mfma_f32_16x16x32_bf16(a[m], b[n], acc[m][n], 0, 0, 0);
    }
    __builtin_amdgcn_s_setprio(0);

    __builtin_amdgcn_sched_barrier(0);
    __builtin_amdgcn_s_barrier();                        // all waves done reading buf pb
    if (kt + 2 < nk) stage(kt + 2, cA, cB);              // restage same-parity buffer
  }

  // C/D layout (m89-verified): col = lane&15, row = (lane>>4)*4 + j
  const int cr = l4 * 4;
#pragma unroll
  for (int m = 0; m < 8; ++m) {
    const int rbase = bm * BM + wr + m * 16;
#pragma unroll
    for (int n = 0; n < 4; ++n) {
      const int c = bn * BN + wc + n * 16 + lm;
      const float bc = (EPI == 2) ? bias[c] : 0.0f;
#pragma unroll
      for (int j = 0; j < 4; ++j) {
        const int r = rbase + cr + j;
        const size_t idx = (size_t)r * N + c;
        const float v = acc[m][n][j];
        if (EPI == 2) {
          Cb[idx] = __float2bfloat16(fast_gelu(v + bc));
        } else {
          Cf[idx] = v;
        }
      }
    }
  }
}

// ---------------- LN(y0+y1+b2) fused with residual: out = z + tanh(alpha)*ln ----------------
__global__ __launch_bounds__(256) void k_ln_res(const float* __restrict__ y0,
                                                const float* __restrict__ y1,
                                                const float* __restrict__ b2,
                                                const float* __restrict__ z,
                                                const float* __restrict__ gamma,
                                                const float* __restrict__ beta,
                                                const float* __restrict__ alpha,
                                                float* __restrict__ out) {
  const int row = blockIdx.x;
  const int t = threadIdx.x;  // 256 threads * 4 floats = 1024 = D
  const float4 va = reinterpret_cast<const float4*>(y0 + (size_t)row * DD)[t];
  const float4 vb = reinterpret_cast<const float4*>(y1 + (size_t)row * DD)[t];
  const float4 bc = reinterpret_cast<const float4*>(b2)[t];
  float4 v;
  v.x = va.x + vb.x + bc.x; v.y = va.y + vb.y + bc.y;
  v.z = va.z + vb.z + bc.z; v.w = va.w + vb.w + bc.w;
  float s = v.x + v.y + v.z + v.w;
  float q = v.x * v.x + v.y * v.y + v.z * v.z + v.w * v.w;
#pragma unroll
  for (int m = 1; m < 64; m <<= 1) {
    s += __shfl_xor(s, m, 64);
    q += __shfl_xor(q, m, 64);
  }
  __shared__ float ss[4], sq[4];
  if ((t & 63) == 0) { ss[t >> 6] = s; sq[t >> 6] = q; }
  __syncthreads();
  s = ss[0] + ss[1] + ss[2] + ss[3];
  q = sq[0] + sq[1] + sq[2] + sq[3];
  const float mu = s * (1.0f / DD);
  const float var = fmaxf(q * (1.0f / DD) - mu * mu, 0.0f);
  const float rs = rsqrtf(var + 1e-5f);
  const float4 g = reinterpret_cast<const float4*>(gamma)[t];
  const float4 bb = reinterpret_cast<const float4*>(beta)[t];
  const float4 aa = reinterpret_cast<const float4*>(alpha)[t];
  const float4 zz = reinterpret_cast<const float4*>(z + (size_t)row * DD)[t];
  float4 o;
  o.x = zz.x + tanhf(aa.x) * ((v.x - mu) * rs * g.x + bb.x);
  o.y = zz.y + tanhf(aa.y) * ((v.y - mu) * rs * g.y + bb.y);
  o.z = zz.z + tanhf(aa.z) * ((v.z - mu) * rs * g.z + bb.z);
  o.w = zz.w + tanhf(aa.w) * ((v.w - mu) * rs * g.w + bb.w);
  reinterpret_cast<float4*>(out + (size_t)row * DD)[t] = o;
}

extern "C" void kernel_launch(void* const* d_in, const int* in_sizes, int n_in, void* d_out,
                              int out_size, void* d_ws, size_t ws_size, hipStream_t stream) {
  const float* x   = (const float*)d_in[0];
  const float* thQ = (const float*)d_in[1];
  const float* W1  = (const float*)d_in[2];
  const float* b1  = (const float*)d_in[3];
  const float* W2  = (const float*)d_in[4];
  const float* b2  = (const float*)d_in[5];
  const float* gam = (const float*)d_in[6];
  const float* bet = (const float*)d_in[7];
  const float* alp = (const float*)d_in[8];
  float* out = (float*)d_out;

  const int M = in_sizes[0] / DD;  // B*V*T = 8192
  constexpr int SMEM = 4 * 256 * 64 * 2;  // 128 KiB dynamic LDS for k_gemm_256

  // allow >64KB dynamic LDS (not a stream op; capture-safe; idempotent)
  hipFuncSetAttribute((const void*)(k_gemm_256<2>),
                      hipFuncAttributeMaxDynamicSharedMemorySize, SMEM);
  hipFuncSetAttribute((const void*)(k_gemm_256<3>),
                      hipFuncAttributeMaxDynamicSharedMemorySize, SMEM);

  char* ws = (char*)d_ws;
  size_t off = 0;
  auto take = [&](size_t bytes) -> char* {
    char* p = ws + off;
    off += (bytes + 255) & ~(size_t)255;
    return p;
  };
  bf16_t* xh  = (bf16_t*)take((size_t)M * DD * 2);
  bf16_t* xl  = (bf16_t*)take((size_t)M * DD * 2);
  bf16_t* qTh = (bf16_t*)take((size_t)DD * DD * 2);
  bf16_t* qTl = (bf16_t*)take((size_t)DD * DD * 2);
  bf16_t* w1T = (bf16_t*)take((size_t)DD * HH * 2);
  bf16_t* w2T = (bf16_t*)take((size_t)HH * DD * 2);
  float*  zf  = (float*)take((size_t)M * DD * 4);
  bf16_t* zb  = (bf16_t*)take((size_t)M * DD * 2);
  bf16_t* hb  = (bf16_t*)take((size_t)M * HH * 2);
  float*  yf  = (float*)take((size_t)M * DD * 4 * 2);  // 2 split-K partials

  // prep: conversions / transposes
  hipLaunchKernelGGL(k_split_x, dim3(2048), dim3(256), 0, stream, x, xh, xl, M * DD / 4);
  hipLaunchKernelGGL((k_transpose<true>), dim3(DD / 32, DD / 32), dim3(32, 8), 0, stream,
                     thQ, qTh, qTl, DD, DD);
  hipLaunchKernelGGL((k_transpose<false>), dim3(HH / 32, DD / 32), dim3(32, 8), 0, stream,
                     W1, w1T, (bf16_t*)nullptr, DD, HH);
  hipLaunchKernelGGL((k_transpose<false>), dim3(DD / 32, HH / 32), dim3(32, 8), 0, stream,
                     W2, w2T, (bf16_t*)nullptr, HH, DD);

  // z = x @ thetaQ  (split 3-pass, BK=32, counted-vmcnt depth-2 pipeline)
  hipLaunchKernelGGL(k_gemm_split, dim3((M / 128) * (DD / 128)), dim3(256), 0, stream,
                     xh, xl, qTh, qTl, zf, zb, M, DD, DD);
  // h = gelu(z @ W1 + b1)   (256^2 BK=64, conflict-free, 128KiB LDS)
  hipLaunchKernelGGL((k_gemm_256<2>), dim3((M / 256) * (HH / 256)), dim3(512), SMEM, stream,
                     zb, w1T, b1, (float*)nullptr, hb, M, HH, DD, DD);
  // y = h @ W2 (split-K=2 raw partials; bias in LN)
  hipLaunchKernelGGL((k_gemm_256<3>), dim3((M / 256) * (DD / 256), 2), dim3(512), SMEM, stream,
                     hb, w2T, (const float*)nullptr, yf, (bf16_t*)nullptr, M, DD, HH / 2, HH);
  // out = z + tanh(alpha) * LayerNorm(y0+y1+b2)
  hipLaunchKernelGGL(k_ln_res, dim3(M), dim3(256), 0, stream,
                     yf, yf + (size_t)M * DD, b2, zf, gam, bet, alp, out);
}